// Round 13
// baseline (239.348 us; speedup 1.0000x reference)
//
#include <hip/hip_runtime.h>
#include <hip/hip_bf16.h>
#include <math.h>

#define NUM_HEADS 8
#define SEQ_L 1024
#define EPS 1e-5f
#define LOG2E 1.44269504088896f
#define KVB 128

typedef __bf16 bf16x8 __attribute__((ext_vector_type(8)));
typedef float f32x4 __attribute__((ext_vector_type(4)));
typedef __hip_bfloat16 bf16;

#define AS1 __attribute__((address_space(1)))
#define AS3 __attribute__((address_space(3)))

__device__ __forceinline__ void gload_lds16(const void* g, void* l) {
    __builtin_amdgcn_global_load_lds((const AS1 unsigned*)g, (AS3 unsigned*)l, 16, 0, 0);
}

__device__ __forceinline__ unsigned short bfb(float x) {
    bf16 b = __float2bfloat16(x);
    return *(unsigned short*)&b;
}

// XOR swizzle for [R][64] bf16 LDS tiles: elem ^= ((row&7)<<3)
__device__ __forceinline__ int swz(int el, int row) { return el ^ ((row & 7) << 3); }
// XOR swizzle for [R][32] bf16 LDS tiles (4 granules/row): elem ^= ((row&3)<<3)
__device__ __forceinline__ int swz2(int el, int row) { return el ^ ((row & 3) << 3); }

// ------------------------------------------------------------------
// Fused prep: h fp32->bf16 copy + 4 weight transposes (fp32->bf16).
// ------------------------------------------------------------------
__global__ __launch_bounds__(256) void prep_kernel(
    const float* __restrict__ h, const float* __restrict__ Wqkv,
    const float* __restrict__ Wo, const float* __restrict__ W1,
    const float* __restrict__ W2,
    bf16* __restrict__ hb, bf16* __restrict__ Wtq, bf16* __restrict__ Wto,
    bf16* __restrict__ Wt1, bf16* __restrict__ Wt2)
{
    const int bid = blockIdx.x;
    const int tid = threadIdx.x;
    if (bid < 2048) {
        const int i = (bid * 256 + tid) * 8;
        const float4 v0 = *(const float4*)&h[i];
        const float4 v1 = *(const float4*)&h[i + 4];
        uint4 w;
        w.x = (unsigned)bfb(v0.x) | ((unsigned)bfb(v0.y) << 16);
        w.y = (unsigned)bfb(v0.z) | ((unsigned)bfb(v0.w) << 16);
        w.z = (unsigned)bfb(v1.x) | ((unsigned)bfb(v1.y) << 16);
        w.w = (unsigned)bfb(v1.z) | ((unsigned)bfb(v1.w) << 16);
        *(uint4*)&hb[i] = w;
        return;
    }
    int r = bid - 2048;
    const float* W; bf16* Wt; int K, N, bx, by;
    if (r < 768)        { W = Wqkv; Wt = Wtq; K = 512;  N = 1536; bx = r % 48; by = r / 48; }
    else if (r < 1024)  { r -= 768;  W = Wo; Wt = Wto; K = 512;  N = 512;  bx = r % 16; by = r / 16; }
    else if (r < 2048)  { r -= 1024; W = W1; Wt = Wt1; K = 512;  N = 2048; bx = r % 64; by = r / 64; }
    else                { r -= 2048; W = W2; Wt = Wt2; K = 2048; N = 512;  bx = r % 16; by = r / 16; }

    __shared__ float t[32][33];
    const int tx = tid & 31, ty = tid >> 5;
    const int n0 = bx * 32, k0 = by * 32;
    #pragma unroll
    for (int q = 0; q < 4; ++q)
        t[ty + 8 * q][tx] = W[(size_t)(k0 + ty + 8 * q) * N + n0 + tx];
    __syncthreads();
    #pragma unroll
    for (int q = 0; q < 4; ++q)
        Wt[(size_t)(n0 + ty + 8 * q) * K + k0 + tx] = __float2bfloat16(t[tx][ty + 8 * q]);
}

// ------------------------------------------------------------------
// bf16 MFMA GEMM (m97 structure): Cb[M,N] = bf16(A @ Bt^T + bias).
// Grid transposed for XCD L2 locality (blockIdx.x = M-tile).
// ------------------------------------------------------------------
__global__ __launch_bounds__(256) void gemm_bf16(
    const bf16* __restrict__ A, const bf16* __restrict__ Bt,
    const float* __restrict__ bias, bf16* __restrict__ Cb,
    int M, int N, int K, int relu)
{
    __shared__ __align__(16) bf16 Abuf[128 * 32];
    __shared__ __align__(16) bf16 Bbuf[128 * 32];
    const int tid = threadIdx.x;
    const int wv = tid >> 6, lane = tid & 63;
    const int row0 = blockIdx.x * 128, col0 = blockIdx.y * 128;
    const int wm = (wv >> 1) * 64, wn = (wv & 1) * 64;
    const int r0 = lane & 15, kb = lane >> 4;

    f32x4 acc[4][4] = {};
    const int arow = lane >> 2;
    const int akoff = (lane & 3) * 8;

    for (int k0 = 0; k0 < K; k0 += 32) {
        #pragma unroll
        for (int s = 0; s < 2; ++s) {
            const int c = 2 * wv + s;
            gload_lds16(&A[(size_t)(row0 + c * 16 + arow) * K + k0 + akoff], &Abuf[c * 512]);
            gload_lds16(&Bt[(size_t)(col0 + c * 16 + arow) * K + k0 + akoff], &Bbuf[c * 512]);
        }
        __syncthreads();

        bf16x8 a[4], b[4];
        #pragma unroll
        for (int i = 0; i < 4; ++i)
            a[i] = *(const bf16x8*)&Abuf[(wm + i * 16 + r0) * 32 + kb * 8];
        #pragma unroll
        for (int j = 0; j < 4; ++j)
            b[j] = *(const bf16x8*)&Bbuf[(wn + j * 16 + r0) * 32 + kb * 8];
        #pragma unroll
        for (int i = 0; i < 4; ++i)
            #pragma unroll
            for (int j = 0; j < 4; ++j)
                acc[i][j] = __builtin_amdgcn_mfma_f32_16x16x32_bf16(a[i], b[j], acc[i][j], 0, 0, 0);
        __syncthreads();
    }

    float bv[4];
    #pragma unroll
    for (int j = 0; j < 4; ++j) bv[j] = bias[col0 + wn + j * 16 + r0];

    #pragma unroll
    for (int i = 0; i < 4; ++i) {
        #pragma unroll
        for (int j = 0; j < 4; ++j) {
            const int col = col0 + wn + j * 16 + r0;
            #pragma unroll
            for (int reg = 0; reg < 4; ++reg) {
                const int row = row0 + wm + i * 16 + kb * 4 + reg;
                float v = acc[i][j][reg] + bv[j];
                if (relu) v = fmaxf(v, 0.f);
                Cb[(size_t)row * N + col] = __float2bfloat16(v);
            }
        }
    }
}

// ------------------------------------------------------------------
// QKV GEMM (grid transposed) with split epilogue -> Qb/Kb/Vtb.
// ------------------------------------------------------------------
__global__ __launch_bounds__(256) void gemm_qkv(
    const bf16* __restrict__ A, const bf16* __restrict__ Bt,
    const float* __restrict__ bias,
    bf16* __restrict__ Qb, bf16* __restrict__ Kb, bf16* __restrict__ Vtb,
    int M, int N, int K)
{
    __shared__ __align__(16) bf16 Abuf[128 * 32];
    __shared__ __align__(16) bf16 Bbuf[128 * 32];
    const int tid = threadIdx.x;
    const int wv = tid >> 6, lane = tid & 63;
    const int row0 = blockIdx.x * 128, col0 = blockIdx.y * 128;
    const int wm = (wv >> 1) * 64, wn = (wv & 1) * 64;
    const int r0 = lane & 15, kb = lane >> 4;

    f32x4 acc[4][4] = {};
    const int arow = lane >> 2;
    const int akoff = (lane & 3) * 8;

    for (int k0 = 0; k0 < K; k0 += 32) {
        #pragma unroll
        for (int s = 0; s < 2; ++s) {
            const int c = 2 * wv + s;
            gload_lds16(&A[(size_t)(row0 + c * 16 + arow) * K + k0 + akoff], &Abuf[c * 512]);
            gload_lds16(&Bt[(size_t)(col0 + c * 16 + arow) * K + k0 + akoff], &Bbuf[c * 512]);
        }
        __syncthreads();

        bf16x8 a[4], b[4];
        #pragma unroll
        for (int i = 0; i < 4; ++i)
            a[i] = *(const bf16x8*)&Abuf[(wm + i * 16 + r0) * 32 + kb * 8];
        #pragma unroll
        for (int j = 0; j < 4; ++j)
            b[j] = *(const bf16x8*)&Bbuf[(wn + j * 16 + r0) * 32 + kb * 8];
        #pragma unroll
        for (int i = 0; i < 4; ++i)
            #pragma unroll
            for (int j = 0; j < 4; ++j)
                acc[i][j] = __builtin_amdgcn_mfma_f32_16x16x32_bf16(a[i], b[j], acc[i][j], 0, 0, 0);
        __syncthreads();
    }

    #pragma unroll
    for (int i = 0; i < 4; ++i) {
        #pragma unroll
        for (int j = 0; j < 4; ++j) {
            const int col = col0 + wn + j * 16 + r0;     // 0..1535
            const float bv = bias[col];
            const int region = col >> 9;                  // 0=q 1=k 2=v
            const int cc = col & 511;
            const int head = cc >> 6, d = cc & 63;
            const int l0 = row0 + wm + i * 16 + kb * 4;
            const int b_ = l0 >> 10, l_ = l0 & 1023;
            if (region == 2) {
                unsigned short pk[4];
                #pragma unroll
                for (int reg = 0; reg < 4; ++reg) pk[reg] = bfb(acc[i][j][reg] + bv);
                *(ushort4*)&Vtb[((size_t)(b_ * NUM_HEADS + head) * 64 + d) * SEQ_L + l_] =
                    make_ushort4(pk[0], pk[1], pk[2], pk[3]);
            } else {
                const float s = (region == 0) ? (0.125f * LOG2E) : 1.0f;
                bf16* dst = (region == 0) ? Qb : Kb;
                #pragma unroll
                for (int reg = 0; reg < 4; ++reg) {
                    dst[((size_t)(b_ * NUM_HEADS + head) * SEQ_L + l_ + reg) * 64 + d] =
                        __float2bfloat16((acc[i][j][reg] + bv) * s);
                }
            }
        }
    }
}

// ------------------------------------------------------------------
// Fused proj + LN1: h1b = bf16(LN(h + A@Wto^T + bo) * g1 + be1).
// 16 rows x 512 cols per block (full row width -> in-block LN).
// A [M,512] bf16, Bt [512][512] bf16. 512 blocks.
// ------------------------------------------------------------------
__global__ __launch_bounds__(256) void gemm_proj_ln(
    const bf16* __restrict__ A, const bf16* __restrict__ Bt,
    const float* __restrict__ bias, const float* __restrict__ resid,
    const float* __restrict__ gamma, const float* __restrict__ beta,
    bf16* __restrict__ outb)
{
    __shared__ __align__(16) bf16 Abuf[16 * 32];     // 1KB
    __shared__ __align__(16) bf16 Bbuf[512 * 32];    // 32KB
    __shared__ float red[4][16][2];
    const int tid = threadIdx.x;
    const int wv = tid >> 6, lane = tid & 63;
    const int r0 = lane & 15, kb = lane >> 4;
    const int row0 = blockIdx.x * 16;

    f32x4 acc[8] = {};

    for (int k0 = 0; k0 < 512; k0 += 32) {
        // A tile (wave 0): 64 chunks, pre-swizzled source (row&3)
        if (wv == 0) {
            const int row = lane >> 2;
            const int gp = (lane & 3) ^ (row & 3);
            gload_lds16(&A[(size_t)(row0 + row) * 512 + k0 + gp * 8], Abuf);
        }
        // B tile: 4 waves x 8 instrs, 64 chunks each
        #pragma unroll
        for (int it = 0; it < 8; ++it) {
            const int ch = (wv * 8 + it) * 64 + lane;
            const int row = ch >> 2;
            const int gp = (ch & 3) ^ (row & 3);
            gload_lds16(&Bt[(size_t)row * 512 + k0 + gp * 8],
                        &Bbuf[(wv * 8 + it) * 512]);
        }
        __syncthreads();

        const bf16x8 a = *(const bf16x8*)&Abuf[swz2(r0 * 32 + kb * 8, r0)];
        #pragma unroll
        for (int j = 0; j < 8; ++j) {
            const int brow = wv * 128 + j * 16 + r0;
            const bf16x8 b = *(const bf16x8*)&Bbuf[swz2(brow * 32 + kb * 8, brow)];
            acc[j] = __builtin_amdgcn_mfma_f32_16x16x32_bf16(a, b, acc[j], 0, 0, 0);
        }
        __syncthreads();
    }

    // epilogue: bias + resid, LN over the full 512-wide row
    const int colbase = wv * 128;
    float ga[8], be[8], bv[8];
    #pragma unroll
    for (int j = 0; j < 8; ++j) {
        const int col = colbase + j * 16 + r0;
        bv[j] = bias[col];
        ga[j] = gamma[col];
        be[j] = beta[col];
    }

    float v[8][4];
    float s[4] = {}, sq[4] = {};
    #pragma unroll
    for (int j = 0; j < 8; ++j) {
        const int col = colbase + j * 16 + r0;
        #pragma unroll
        for (int reg = 0; reg < 4; ++reg) {
            const int row = row0 + kb * 4 + reg;
            const float val = acc[j][reg] + bv[j] + resid[(size_t)row * 512 + col];
            v[j][reg] = val;
            s[reg] += val;
            sq[reg] += val * val;
        }
    }
    #pragma unroll
    for (int off = 1; off < 16; off <<= 1) {
        #pragma unroll
        for (int reg = 0; reg < 4; ++reg) {
            s[reg] += __shfl_xor(s[reg], off, 64);
            sq[reg] += __shfl_xor(sq[reg], off, 64);
        }
    }
    if (r0 == 0) {
        #pragma unroll
        for (int reg = 0; reg < 4; ++reg) {
            red[wv][kb * 4 + reg][0] = s[reg];
            red[wv][kb * 4 + reg][1] = sq[reg];
        }
    }
    __syncthreads();
    #pragma unroll
    for (int reg = 0; reg < 4; ++reg) {
        const int r = kb * 4 + reg;
        const float st = red[0][r][0] + red[1][r][0] + red[2][r][0] + red[3][r][0];
        const float sqt = red[0][r][1] + red[1][r][1] + red[2][r][1] + red[3][r][1];
        const float mu = st * (1.f / 512.f);
        const float var = sqt * (1.f / 512.f) - mu * mu;
        const float rstd = rsqrtf(var + EPS);
        #pragma unroll
        for (int j = 0; j < 8; ++j) {
            const int col = colbase + j * 16 + r0;
            const float rr = (v[j][reg] - mu) * rstd * ga[j] + be[j];
            outb[(size_t)(row0 + r) * 512 + col] = __float2bfloat16(rr);
        }
    }
}

// ------------------------------------------------------------------
// MFMA flash attention (r10 version — best measured):
//  - grid (bh, qtile), XCD-pinned K/V; KVB=128; single-buffer
//    global_load_lds staging (pre-swizzled source); bias+mask
//    register prefetch; defer-max; per-lane partial l; log2 softmax.
// ------------------------------------------------------------------
__global__ __launch_bounds__(256) void attn_mfma(
    const bf16* __restrict__ Qb, const bf16* __restrict__ Kb,
    const bf16* __restrict__ Vtb, const float* __restrict__ abias,
    const int* __restrict__ mask, bf16* __restrict__ out)
{
    const int bh = blockIdx.x;               // 0..63  (XCD = bh%8)
    const int b = bh >> 3, h = bh & 7;
    const int q0 = blockIdx.y * 64;
    const int tid = threadIdx.x;
    const int wv = tid >> 6, lane = tid & 63;
    const int ql = lane & 15;
    const int hi = lane >> 4;

    __shared__ __align__(16) bf16 Ks[KVB * 64];
    __shared__ __align__(16) bf16 Vs[64 * KVB];
    __shared__ __align__(16) bf16 Ps[4][16 * KVB];

    const bf16* Kbase = Kb + (size_t)bh * SEQ_L * 64;
    const bf16* Vbase = Vtb + (size_t)bh * 64 * SEQ_L;
    const int* mbase = mask + b * SEQ_L;

    auto stageKV = [&](int k0) {
        #pragma unroll
        for (int it = 0; it < 4; ++it) {
            const int row = wv * 32 + it * 8 + (lane >> 3);
            const int gp = (lane & 7) ^ (row & 7);
            gload_lds16(&Kbase[(size_t)(k0 + row) * 64 + gp * 8],
                        &Ks[(wv * 32 + it * 8) * 64]);
        }
        #pragma unroll
        for (int it = 0; it < 4; ++it) {
            const int row = wv * 16 + it * 4 + (lane >> 4);
            const int g = lane & 15;
            const int gp = (g & 8) | ((g & 7) ^ (row & 7));
            gload_lds16(&Vbase[(size_t)row * SEQ_L + k0 + gp * 8],
                        &Vs[(wv * 16 + it * 4) * KVB]);
        }
    };

    const int qrow = q0 + wv * 16 + ql;
    bf16x8 qf[2];
    #pragma unroll
    for (int kk = 0; kk < 2; ++kk)
        qf[kk] = *(const bf16x8*)&Qb[((size_t)bh * SEQ_L + qrow) * 64 + kk * 32 + hi * 8];

    const size_t bias_row = ((size_t)(b * NUM_HEADS + h) * SEQ_L + qrow) * SEQ_L;

    f32x4 breg[8];
    auto loadBias = [&](int k0) {
        #pragma unroll
        for (int c = 0; c < 8; ++c)
            breg[c] = *(const f32x4*)&abias[bias_row + k0 + c * 16 + hi * 4];
    };
    int4 mfr[8];
    auto loadMask = [&](int k0) {
        #pragma unroll
        for (int c = 0; c < 8; ++c)
            mfr[c] = *(const int4*)&mbase[k0 + c * 16 + hi * 4];
    };

    f32x4 o[4] = {};
    float m = -1e30f, l = 0.f;

    stageKV(0);
    loadBias(0);
    loadMask(0);
    __syncthreads();

    for (int t = 0; t < 8; ++t) {
        f32x4 p[8];
        #pragma unroll
        for (int c = 0; c < 8; ++c) {
            p[c][0] = (mfr[c].x > 0) ? breg[c][0] * LOG2E : -1e30f;
            p[c][1] = (mfr[c].y > 0) ? breg[c][1] * LOG2E : -1e30f;
            p[c][2] = (mfr[c].z > 0) ? breg[c][2] * LOG2E : -1e30f;
            p[c][3] = (mfr[c].w > 0) ? breg[c][3] * LOG2E : -1e30f;
        }

        if (t < 7) { loadBias((t + 1) * KVB); loadMask((t + 1) * KVB); }

        __builtin_amdgcn_s_setprio(1);
        #pragma unroll
        for (int c = 0; c < 8; ++c) {
            const int row = c * 16 + ql;
            #pragma unroll
            for (int kk = 0; kk < 2; ++kk) {
                const bf16x8 kf = *(const bf16x8*)&Ks[swz(row * 64 + kk * 32 + hi * 8, row)];
                p[c] = __builtin_amdgcn_mfma_f32_16x16x32_bf16(kf, qf[kk], p[c], 0, 0, 0);
            }
        }
        __builtin_amdgcn_s_setprio(0);

        float mx = p[0][0];
        #pragma unroll
        for (int c = 0; c < 8; ++c)
            #pragma unroll
            for (int reg = 0; reg < 4; ++reg) mx = fmaxf(mx, p[c][reg]);
        mx = fmaxf(mx, __shfl_xor(mx, 16, 64));
        mx = fmaxf(mx, __shfl_xor(mx, 32, 64));

        if (!__all(mx <= m + 11.0f)) {
            const float mnew = fmaxf(m, mx);
            const float scale = __builtin_exp2f(m - mnew);
            m = mnew;
            l *= scale;
            #pragma unroll
            for (int reg = 0; reg < 4; ++reg) {
                const float sc_q = __shfl(scale, (lane & 48) | (hi * 4 + reg), 64);
                #pragma unroll
                for (int c2 = 0; c2 < 4; ++c2) o[c2][reg] *= sc_q;
            }
        }

        float lsum = 0.f;
        #pragma unroll
        for (int c = 0; c < 8; ++c)
            #pragma unroll
            for (int reg = 0; reg < 4; ++reg) {
                const float pv = __builtin_exp2f(p[c][reg] - m);
                p[c][reg] = pv;
                lsum += pv;
            }
        l += lsum;

        #pragma unroll
        for (int c = 0; c < 8; ++c) {
            const int el = ql * KVB + c * 16 + hi * 4;
            uint2 pk;
            pk.x = (unsigned)bfb(p[c][0]) | ((unsigned)bfb(p[c][1]) << 16);
            pk.y = (unsigned)bfb(p[c][2]) | ((unsigned)bfb(p[c][3]) << 16);
            *(uint2*)&Ps[wv][swz(el, ql)] = pk;
        }

        __builtin_amdgcn_s_setprio(1);
        #pragma unroll
        for (int kk = 0; kk < 4; ++kk) {
            const bf16x8 pf = *(const bf16x8*)&Ps[wv][swz(ql * KVB + kk * 32 + hi * 8, ql)];
            #pragma unroll
            for (int c2 = 0; c2 < 4; ++c2) {
                const int vrow = c2 * 16 + ql;
                const bf16x8 vf = *(const bf16x8*)&Vs[swz(vrow * KVB + kk * 32 + hi * 8, vrow)];
                o[c2] = __builtin_amdgcn_mfma_f32_16x16x32_bf16(pf, vf, o[c2], 0, 0, 0);
            }
        }
        __builtin_amdgcn_s_setprio(0);

        if (t < 7) {
            __syncthreads();
            stageKV((t + 1) * KVB);
            __syncthreads();
        }
    }

    l += __shfl_xor(l, 16, 64);
    l += __shfl_xor(l, 32, 64);
    const float invl = (l > 0.f) ? (1.0f / l) : 0.f;
    #pragma unroll
    for (int reg = 0; reg < 4; ++reg) {
        const float inv_q = __shfl(invl, (lane & 48) | (hi * 4 + reg), 64);
        const int row = q0 + wv * 16 + hi * 4 + reg;
        #pragma unroll
        for (int c2 = 0; c2 < 4; ++c2)
            out[((size_t)(b * SEQ_L + row)) * 512 + h * 64 + c2 * 16 + ql] =
                __float2bfloat16(o[c2][reg] * inv_q);
    }
}

// ------------------------------------------------------------------
// out fp32 = LayerNorm(h1b bf16 + f2b bf16)
// ------------------------------------------------------------------
__global__ __launch_bounds__(256) void add_ln_from_bf16(
    const bf16* __restrict__ Xb, const bf16* __restrict__ Yb,
    const float* __restrict__ gamma, const float* __restrict__ beta,
    float* __restrict__ out)
{
    const int wave = threadIdx.x >> 6;
    const int lane = threadIdx.x & 63;
    const int row = blockIdx.x * 4 + wave;
    const bf16x8 xv = *(const bf16x8*)&Xb[(size_t)row * 512 + lane * 8];
    const bf16x8 yv = *(const bf16x8*)&Yb[(size_t)row * 512 + lane * 8];

    float v[8];
    #pragma unroll
    for (int i = 0; i < 8; ++i) v[i] = (float)xv[i] + (float)yv[i];

    float s = 0.f, sq = 0.f;
    #pragma unroll
    for (int i = 0; i < 8; ++i) { s += v[i]; sq += v[i] * v[i]; }
    #pragma unroll
    for (int off = 1; off < 64; off <<= 1) {
        s += __shfl_xor(s, off, 64);
        sq += __shfl_xor(sq, off, 64);
    }
    const float mu = s * (1.f / 512.f);
    const float var = sq * (1.f / 512.f) - mu * mu;
    const float rstd = rsqrtf(var + EPS);

    const int c = lane * 8;
    const float4 g0 = *(const float4*)&gamma[c];
    const float4 g1 = *(const float4*)&gamma[c + 4];
    const float4 e0 = *(const float4*)&beta[c];
    const float4 e1 = *(const float4*)&beta[c + 4];
    float4 r0, r1;
    r0.x = (v[0] - mu) * rstd * g0.x + e0.x;
    r0.y = (v[1] - mu) * rstd * g0.y + e0.y;
    r0.z = (v[2] - mu) * rstd * g0.z + e0.z;
    r0.w = (v[3] - mu) * rstd * g0.w + e0.w;
    r1.x = (v[4] - mu) * rstd * g1.x + e1.x;
    r1.y = (v[5] - mu) * rstd * g1.y + e1.y;
    r1.z = (v[6] - mu) * rstd * g1.z + e1.z;
    r1.w = (v[7] - mu) * rstd * g1.w + e1.w;
    float* op = out + (size_t)row * 512 + c;
    *(float4*)op = r0;
    *(float4*)(op + 4) = r1;
}

// ------------------------------------------------------------------
extern "C" void kernel_launch(void* const* d_in, const int* in_sizes, int n_in,
                              void* d_out, int out_size, void* d_ws, size_t ws_size,
                              hipStream_t stream)
{
    const float* h    = (const float*)d_in[0];
    const float* ab   = (const float*)d_in[1];
    const int*   mask = (const int*)d_in[2];
    const float* Wqkv = (const float*)d_in[3];
    const float* bqkv = (const float*)d_in[4];
    const float* Wo   = (const float*)d_in[5];
    const float* bo   = (const float*)d_in[6];
    const float* W1   = (const float*)d_in[7];
    const float* b1   = (const float*)d_in[8];
    const float* W2   = (const float*)d_in[9];
    const float* b2   = (const float*)d_in[10];
    const float* g1   = (const float*)d_in[11];
    const float* be1  = (const float*)d_in[12];
    const float* g2   = (const float*)d_in[13];
    const float* be2  = (const float*)d_in[14];
    float* out = (float*)d_out;
    char* ws = (char*)d_ws;

    const int M = 8 * 1024;
    const size_t MB = 1024 * 1024;

    bf16*  hb    = (bf16*)(ws + 0 * MB);    // 8MB
    bf16*  Wtq   = (bf16*)(ws + 8 * MB);    // 1.5MB
    bf16*  Wto   = (bf16*)(ws + 10 * MB);   // 0.5MB
    bf16*  Wt1   = (bf16*)(ws + 11 * MB);   // 2MB
    bf16*  Wt2   = (bf16*)(ws + 13 * MB);   // 2MB
    bf16*  Qb    = (bf16*)(ws + 15 * MB);   // 8MB
    bf16*  Kb    = (bf16*)(ws + 23 * MB);   // 8MB
    bf16*  Vtb   = (bf16*)(ws + 31 * MB);   // 8MB
    bf16*  aob   = (bf16*)(ws + 39 * MB);   // 8MB
    bf16*  h1b   = (bf16*)(ws + 55 * MB);   // 8MB
    bf16*  ffb   = (bf16*)(ws + 63 * MB);   // 32MB
    bf16*  f2b   = (bf16*)(ws + 95 * MB);   // 8MB

    prep_kernel<<<dim3(5120), 256, 0, stream>>>(h, Wqkv, Wo, W1, W2, hb, Wtq, Wto, Wt1, Wt2);
    gemm_qkv<<<dim3(M / 128, 1536 / 128), 256, 0, stream>>>(hb, Wtq, bqkv, Qb, Kb, Vtb, M, 1536, 512);
    attn_mfma<<<dim3(64, SEQ_L / 64), 256, 0, stream>>>(Qb, Kb, Vtb, ab, mask, aob);
    // fused proj + LN1 (writes h1b directly)
    gemm_proj_ln<<<dim3(M / 16), 256, 0, stream>>>(aob, Wto, bo, h, g1, be1, h1b);
    gemm_bf16<<<dim3(M / 128, 2048 / 128), 256, 0, stream>>>(h1b, Wt1, b1, ffb, M, 2048, 512, 1);
    gemm_bf16<<<dim3(M / 128, 512 / 128), 256, 0, stream>>>(ffb, Wt2, b2, f2b, M, 512, 2048, 0);
    add_ln_from_bf16<<<dim3(M / 4), 256, 0, stream>>>(h1b, f2b, g2, be2, out);
}

// Round 14
// 226.762 us; speedup vs baseline: 1.0555x; 1.0555x over previous
//
#include <hip/hip_runtime.h>
#include <hip/hip_bf16.h>
#include <math.h>

#define NUM_HEADS 8
#define SEQ_L 1024
#define EPS 1e-5f
#define LOG2E 1.44269504088896f
#define KVB 128

typedef __bf16 bf16x8 __attribute__((ext_vector_type(8)));
typedef float f32x4 __attribute__((ext_vector_type(4)));
typedef __hip_bfloat16 bf16;

#define AS1 __attribute__((address_space(1)))
#define AS3 __attribute__((address_space(3)))

__device__ __forceinline__ void gload_lds16(const void* g, void* l) {
    __builtin_amdgcn_global_load_lds((const AS1 unsigned*)g, (AS3 unsigned*)l, 16, 0, 0);
}

__device__ __forceinline__ unsigned short bfb(float x) {
    bf16 b = __float2bfloat16(x);
    return *(unsigned short*)&b;
}

// XOR swizzle for row-major bf16 LDS tiles: elem ^= ((row&7)<<3) (16B granules)
__device__ __forceinline__ int swz(int el, int row) { return el ^ ((row & 7) << 3); }

// ------------------------------------------------------------------
// Fused prep: h fp32->bf16 copy + 4 weight transposes (fp32->bf16).
// ------------------------------------------------------------------
__global__ __launch_bounds__(256) void prep_kernel(
    const float* __restrict__ h, const float* __restrict__ Wqkv,
    const float* __restrict__ Wo, const float* __restrict__ W1,
    const float* __restrict__ W2,
    bf16* __restrict__ hb, bf16* __restrict__ Wtq, bf16* __restrict__ Wto,
    bf16* __restrict__ Wt1, bf16* __restrict__ Wt2)
{
    const int bid = blockIdx.x;
    const int tid = threadIdx.x;
    if (bid < 2048) {
        const int i = (bid * 256 + tid) * 8;
        const float4 v0 = *(const float4*)&h[i];
        const float4 v1 = *(const float4*)&h[i + 4];
        uint4 w;
        w.x = (unsigned)bfb(v0.x) | ((unsigned)bfb(v0.y) << 16);
        w.y = (unsigned)bfb(v0.z) | ((unsigned)bfb(v0.w) << 16);
        w.z = (unsigned)bfb(v1.x) | ((unsigned)bfb(v1.y) << 16);
        w.w = (unsigned)bfb(v1.z) | ((unsigned)bfb(v1.w) << 16);
        *(uint4*)&hb[i] = w;
        return;
    }
    int r = bid - 2048;
    const float* W; bf16* Wt; int K, N, bx, by;
    if (r < 768)        { W = Wqkv; Wt = Wtq; K = 512;  N = 1536; bx = r % 48; by = r / 48; }
    else if (r < 1024)  { r -= 768;  W = Wo; Wt = Wto; K = 512;  N = 512;  bx = r % 16; by = r / 16; }
    else if (r < 2048)  { r -= 1024; W = W1; Wt = Wt1; K = 512;  N = 2048; bx = r % 64; by = r / 64; }
    else                { r -= 2048; W = W2; Wt = Wt2; K = 2048; N = 512;  bx = r % 16; by = r / 16; }

    __shared__ float t[32][33];
    const int tx = tid & 31, ty = tid >> 5;
    const int n0 = bx * 32, k0 = by * 32;
    #pragma unroll
    for (int q = 0; q < 4; ++q)
        t[ty + 8 * q][tx] = W[(size_t)(k0 + ty + 8 * q) * N + n0 + tx];
    __syncthreads();
    #pragma unroll
    for (int q = 0; q < 4; ++q)
        Wt[(size_t)(n0 + ty + 8 * q) * K + k0 + tx] = __float2bfloat16(t[tx][ty + 8 * q]);
}

// ------------------------------------------------------------------
// bf16 MFMA GEMM (m97 structure): Cb[M,N] = bf16(A @ Bt^T + bias).
// Grid transposed for XCD L2 locality (blockIdx.x = M-tile).
// ------------------------------------------------------------------
__global__ __launch_bounds__(256) void gemm_bf16(
    const bf16* __restrict__ A, const bf16* __restrict__ Bt,
    const float* __restrict__ bias, bf16* __restrict__ Cb,
    int M, int N, int K, int relu)
{
    __shared__ __align__(16) bf16 Abuf[128 * 32];
    __shared__ __align__(16) bf16 Bbuf[128 * 32];
    const int tid = threadIdx.x;
    const int wv = tid >> 6, lane = tid & 63;
    const int row0 = blockIdx.x * 128, col0 = blockIdx.y * 128;
    const int wm = (wv >> 1) * 64, wn = (wv & 1) * 64;
    const int r0 = lane & 15, kb = lane >> 4;

    f32x4 acc[4][4] = {};
    const int arow = lane >> 2;
    const int akoff = (lane & 3) * 8;

    for (int k0 = 0; k0 < K; k0 += 32) {
        #pragma unroll
        for (int s = 0; s < 2; ++s) {
            const int c = 2 * wv + s;
            gload_lds16(&A[(size_t)(row0 + c * 16 + arow) * K + k0 + akoff], &Abuf[c * 512]);
            gload_lds16(&Bt[(size_t)(col0 + c * 16 + arow) * K + k0 + akoff], &Bbuf[c * 512]);
        }
        __syncthreads();

        bf16x8 a[4], b[4];
        #pragma unroll
        for (int i = 0; i < 4; ++i)
            a[i] = *(const bf16x8*)&Abuf[(wm + i * 16 + r0) * 32 + kb * 8];
        #pragma unroll
        for (int j = 0; j < 4; ++j)
            b[j] = *(const bf16x8*)&Bbuf[(wn + j * 16 + r0) * 32 + kb * 8];
        #pragma unroll
        for (int i = 0; i < 4; ++i)
            #pragma unroll
            for (int j = 0; j < 4; ++j)
                acc[i][j] = __builtin_amdgcn_mfma_f32_16x16x32_bf16(a[i], b[j], acc[i][j], 0, 0, 0);
        __syncthreads();
    }

    float bv[4];
    #pragma unroll
    for (int j = 0; j < 4; ++j) bv[j] = bias[col0 + wn + j * 16 + r0];

    #pragma unroll
    for (int i = 0; i < 4; ++i) {
        #pragma unroll
        for (int j = 0; j < 4; ++j) {
            const int col = col0 + wn + j * 16 + r0;
            #pragma unroll
            for (int reg = 0; reg < 4; ++reg) {
                const int row = row0 + wm + i * 16 + kb * 4 + reg;
                float v = acc[i][j][reg] + bv[j];
                if (relu) v = fmaxf(v, 0.f);
                Cb[(size_t)row * N + col] = __float2bfloat16(v);
            }
        }
    }
}

// ------------------------------------------------------------------
// QKV GEMM (grid transposed) with split epilogue -> Qb/Kb/Vtb.
// ------------------------------------------------------------------
__global__ __launch_bounds__(256) void gemm_qkv(
    const bf16* __restrict__ A, const bf16* __restrict__ Bt,
    const float* __restrict__ bias,
    bf16* __restrict__ Qb, bf16* __restrict__ Kb, bf16* __restrict__ Vtb,
    int M, int N, int K)
{
    __shared__ __align__(16) bf16 Abuf[128 * 32];
    __shared__ __align__(16) bf16 Bbuf[128 * 32];
    const int tid = threadIdx.x;
    const int wv = tid >> 6, lane = tid & 63;
    const int row0 = blockIdx.x * 128, col0 = blockIdx.y * 128;
    const int wm = (wv >> 1) * 64, wn = (wv & 1) * 64;
    const int r0 = lane & 15, kb = lane >> 4;

    f32x4 acc[4][4] = {};
    const int arow = lane >> 2;
    const int akoff = (lane & 3) * 8;

    for (int k0 = 0; k0 < K; k0 += 32) {
        #pragma unroll
        for (int s = 0; s < 2; ++s) {
            const int c = 2 * wv + s;
            gload_lds16(&A[(size_t)(row0 + c * 16 + arow) * K + k0 + akoff], &Abuf[c * 512]);
            gload_lds16(&Bt[(size_t)(col0 + c * 16 + arow) * K + k0 + akoff], &Bbuf[c * 512]);
        }
        __syncthreads();

        bf16x8 a[4], b[4];
        #pragma unroll
        for (int i = 0; i < 4; ++i)
            a[i] = *(const bf16x8*)&Abuf[(wm + i * 16 + r0) * 32 + kb * 8];
        #pragma unroll
        for (int j = 0; j < 4; ++j)
            b[j] = *(const bf16x8*)&Bbuf[(wn + j * 16 + r0) * 32 + kb * 8];
        #pragma unroll
        for (int i = 0; i < 4; ++i)
            #pragma unroll
            for (int j = 0; j < 4; ++j)
                acc[i][j] = __builtin_amdgcn_mfma_f32_16x16x32_bf16(a[i], b[j], acc[i][j], 0, 0, 0);
        __syncthreads();
    }

    #pragma unroll
    for (int i = 0; i < 4; ++i) {
        #pragma unroll
        for (int j = 0; j < 4; ++j) {
            const int col = col0 + wn + j * 16 + r0;     // 0..1535
            const float bv = bias[col];
            const int region = col >> 9;                  // 0=q 1=k 2=v
            const int cc = col & 511;
            const int head = cc >> 6, d = cc & 63;
            const int l0 = row0 + wm + i * 16 + kb * 4;
            const int b_ = l0 >> 10, l_ = l0 & 1023;
            if (region == 2) {
                unsigned short pk[4];
                #pragma unroll
                for (int reg = 0; reg < 4; ++reg) pk[reg] = bfb(acc[i][j][reg] + bv);
                *(ushort4*)&Vtb[((size_t)(b_ * NUM_HEADS + head) * 64 + d) * SEQ_L + l_] =
                    make_ushort4(pk[0], pk[1], pk[2], pk[3]);
            } else {
                const float s = (region == 0) ? (0.125f * LOG2E) : 1.0f;
                bf16* dst = (region == 0) ? Qb : Kb;
                #pragma unroll
                for (int reg = 0; reg < 4; ++reg) {
                    dst[((size_t)(b_ * NUM_HEADS + head) * SEQ_L + l_ + reg) * 64 + d] =
                        __float2bfloat16((acc[i][j][reg] + bv) * s);
                }
            }
        }
    }
}

// ------------------------------------------------------------------
// MFMA flash attention — 8-wave/512-thread blocks (zero-tail grid):
//  grid = (64 bh, 8 qtiles) = 512 blocks; LDS 64KB -> 2 blocks/CU ->
//  exactly 512 resident (no tail), 16 waves/CU. Per-wave structure
//  identical to r10 (best measured): 16 q-rows/wave, KVB=128,
//  global_load_lds staging (pre-swizzled src), bias+mask reg-prefetch,
//  defer-max, per-lane partial l, log2 softmax.
// ------------------------------------------------------------------
__global__ __launch_bounds__(512) void attn_mfma(
    const bf16* __restrict__ Qb, const bf16* __restrict__ Kb,
    const bf16* __restrict__ Vtb, const float* __restrict__ abias,
    const int* __restrict__ mask, bf16* __restrict__ out)
{
    const int bh = blockIdx.x;               // 0..63  (XCD = bh%8)
    const int b = bh >> 3, h = bh & 7;
    const int q0 = blockIdx.y * 128;
    const int tid = threadIdx.x;
    const int wv = tid >> 6, lane = tid & 63; // wv 0..7
    const int ql = lane & 15;
    const int hi = lane >> 4;

    __shared__ __align__(16) bf16 Ks[KVB * 64];      // 16KB [key][d] swizzled
    __shared__ __align__(16) bf16 Vs[64 * KVB];      // 16KB [d][key] swizzled
    __shared__ __align__(16) bf16 Ps[8][16 * KVB];   // 32KB per-wave P tiles

    const bf16* Kbase = Kb + (size_t)bh * SEQ_L * 64;
    const bf16* Vbase = Vtb + (size_t)bh * 64 * SEQ_L;
    const int* mbase = mask + b * SEQ_L;

    // async K/V stage across 8 waves: 4 global_load_lds per thread
    auto stageKV = [&](int k0) {
        #pragma unroll
        for (int it = 0; it < 2; ++it) {
            const int blk = wv * 2 + it;               // 0..15
            const int row = blk * 8 + (lane >> 3);     // 0..127
            const int gp = (lane & 7) ^ (row & 7);
            gload_lds16(&Kbase[(size_t)(k0 + row) * 64 + gp * 8],
                        &Ks[blk * 512]);
        }
        #pragma unroll
        for (int it = 0; it < 2; ++it) {
            const int blk = wv * 2 + it;               // 0..15
            const int row = blk * 4 + (lane >> 4);     // 0..63
            const int g = lane & 15;
            const int gp = (g & 8) | ((g & 7) ^ (row & 7));
            gload_lds16(&Vbase[(size_t)row * SEQ_L + k0 + gp * 8],
                        &Vs[blk * 512]);
        }
    };

    const int qrow = q0 + wv * 16 + ql;
    bf16x8 qf[2];
    #pragma unroll
    for (int kk = 0; kk < 2; ++kk)
        qf[kk] = *(const bf16x8*)&Qb[((size_t)bh * SEQ_L + qrow) * 64 + kk * 32 + hi * 8];

    const size_t bias_row = ((size_t)(b * NUM_HEADS + h) * SEQ_L + qrow) * SEQ_L;

    f32x4 breg[8];
    auto loadBias = [&](int k0) {
        #pragma unroll
        for (int c = 0; c < 8; ++c)
            breg[c] = *(const f32x4*)&abias[bias_row + k0 + c * 16 + hi * 4];
    };
    int4 mfr[8];
    auto loadMask = [&](int k0) {
        #pragma unroll
        for (int c = 0; c < 8; ++c)
            mfr[c] = *(const int4*)&mbase[k0 + c * 16 + hi * 4];
    };

    f32x4 o[4] = {};
    float m = -1e30f, l = 0.f;

    stageKV(0);
    loadBias(0);
    loadMask(0);
    __syncthreads();   // drains vmcnt: KV(0) in LDS, bias(0)/mask(0) in regs

    for (int t = 0; t < 8; ++t) {
        f32x4 p[8];
        #pragma unroll
        for (int c = 0; c < 8; ++c) {
            p[c][0] = (mfr[c].x > 0) ? breg[c][0] * LOG2E : -1e30f;
            p[c][1] = (mfr[c].y > 0) ? breg[c][1] * LOG2E : -1e30f;
            p[c][2] = (mfr[c].z > 0) ? breg[c][2] * LOG2E : -1e30f;
            p[c][3] = (mfr[c].w > 0) ? breg[c][3] * LOG2E : -1e30f;
        }

        if (t < 7) { loadBias((t + 1) * KVB); loadMask((t + 1) * KVB); }

        __builtin_amdgcn_s_setprio(1);
        #pragma unroll
        for (int c = 0; c < 8; ++c) {
            const int row = c * 16 + ql;
            #pragma unroll
            for (int kk = 0; kk < 2; ++kk) {
                const bf16x8 kf = *(const bf16x8*)&Ks[swz(row * 64 + kk * 32 + hi * 8, row)];
                p[c] = __builtin_amdgcn_mfma_f32_16x16x32_bf16(kf, qf[kk], p[c], 0, 0, 0);
            }
        }
        __builtin_amdgcn_s_setprio(0);

        float mx = p[0][0];
        #pragma unroll
        for (int c = 0; c < 8; ++c)
            #pragma unroll
            for (int reg = 0; reg < 4; ++reg) mx = fmaxf(mx, p[c][reg]);
        mx = fmaxf(mx, __shfl_xor(mx, 16, 64));
        mx = fmaxf(mx, __shfl_xor(mx, 32, 64));

        if (!__all(mx <= m + 11.0f)) {
            const float mnew = fmaxf(m, mx);
            const float scale = __builtin_exp2f(m - mnew);
            m = mnew;
            l *= scale;
            #pragma unroll
            for (int reg = 0; reg < 4; ++reg) {
                const float sc_q = __shfl(scale, (lane & 48) | (hi * 4 + reg), 64);
                #pragma unroll
                for (int c2 = 0; c2 < 4; ++c2) o[c2][reg] *= sc_q;
            }
        }

        float lsum = 0.f;
        #pragma unroll
        for (int c = 0; c < 8; ++c)
            #pragma unroll
            for (int reg = 0; reg < 4; ++reg) {
                const float pv = __builtin_exp2f(p[c][reg] - m);
                p[c][reg] = pv;
                lsum += pv;
            }
        l += lsum;

        #pragma unroll
        for (int c = 0; c < 8; ++c) {
            const int el = ql * KVB + c * 16 + hi * 4;
            uint2 pk;
            pk.x = (unsigned)bfb(p[c][0]) | ((unsigned)bfb(p[c][1]) << 16);
            pk.y = (unsigned)bfb(p[c][2]) | ((unsigned)bfb(p[c][3]) << 16);
            *(uint2*)&Ps[wv][swz(el, ql)] = pk;
        }

        __builtin_amdgcn_s_setprio(1);
        #pragma unroll
        for (int kk = 0; kk < 4; ++kk) {
            const bf16x8 pf = *(const bf16x8*)&Ps[wv][swz(ql * KVB + kk * 32 + hi * 8, ql)];
            #pragma unroll
            for (int c2 = 0; c2 < 4; ++c2) {
                const int vrow = c2 * 16 + ql;
                const bf16x8 vf = *(const bf16x8*)&Vs[swz(vrow * KVB + kk * 32 + hi * 8, vrow)];
                o[c2] = __builtin_amdgcn_mfma_f32_16x16x32_bf16(pf, vf, o[c2], 0, 0, 0);
            }
        }
        __builtin_amdgcn_s_setprio(0);

        if (t < 7) {
            __syncthreads();              // all waves done with KV(t)
            stageKV((t + 1) * KVB);       // async DMA into same buffers
            __syncthreads();              // drains vmcnt -> KV(t+1) ready
        }
    }

    l += __shfl_xor(l, 16, 64);
    l += __shfl_xor(l, 32, 64);
    const float invl = (l > 0.f) ? (1.0f / l) : 0.f;
    #pragma unroll
    for (int reg = 0; reg < 4; ++reg) {
        const float inv_q = __shfl(invl, (lane & 48) | (hi * 4 + reg), 64);
        const int row = q0 + wv * 16 + hi * 4 + reg;
        #pragma unroll
        for (int c2 = 0; c2 < 4; ++c2)
            out[((size_t)(b * SEQ_L + row)) * 512 + h * 64 + c2 * 16 + ql] =
                __float2bfloat16(o[c2][reg] * inv_q);
    }
}

// ------------------------------------------------------------------
// h1b = bf16(LayerNorm(h fp32 + projb bf16))
// ------------------------------------------------------------------
__global__ __launch_bounds__(256) void add_ln_to_bf16(
    const float* __restrict__ X, const bf16* __restrict__ Yb,
    const float* __restrict__ gamma, const float* __restrict__ beta,
    bf16* __restrict__ outb)
{
    const int wave = threadIdx.x >> 6;
    const int lane = threadIdx.x & 63;
    const int row = blockIdx.x * 4 + wave;
    const float* xp = X + (size_t)row * 512 + lane * 8;
    const bf16x8 yv = *(const bf16x8*)&Yb[(size_t)row * 512 + lane * 8];

    float v[8];
    const float4 a0 = *(const float4*)xp;
    const float4 a1 = *(const float4*)(xp + 4);
    v[0] = a0.x + (float)yv[0]; v[1] = a0.y + (float)yv[1];
    v[2] = a0.z + (float)yv[2]; v[3] = a0.w + (float)yv[3];
    v[4] = a1.x + (float)yv[4]; v[5] = a1.y + (float)yv[5];
    v[6] = a1.z + (float)yv[6]; v[7] = a1.w + (float)yv[7];

    float s = 0.f, sq = 0.f;
    #pragma unroll
    for (int i = 0; i < 8; ++i) { s += v[i]; sq += v[i] * v[i]; }
    #pragma unroll
    for (int off = 1; off < 64; off <<= 1) {
        s += __shfl_xor(s, off, 64);
        sq += __shfl_xor(sq, off, 64);
    }
    const float mu = s * (1.f / 512.f);
    const float var = sq * (1.f / 512.f) - mu * mu;
    const float rstd = rsqrtf(var + EPS);

    const int c = lane * 8;
    const float4 g0 = *(const float4*)&gamma[c];
    const float4 g1 = *(const float4*)&gamma[c + 4];
    const float4 e0 = *(const float4*)&beta[c];
    const float4 e1 = *(const float4*)&beta[c + 4];
    float r[8];
    r[0] = (v[0] - mu) * rstd * g0.x + e0.x;
    r[1] = (v[1] - mu) * rstd * g0.y + e0.y;
    r[2] = (v[2] - mu) * rstd * g0.z + e0.z;
    r[3] = (v[3] - mu) * rstd * g0.w + e0.w;
    r[4] = (v[4] - mu) * rstd * g1.x + e1.x;
    r[5] = (v[5] - mu) * rstd * g1.y + e1.y;
    r[6] = (v[6] - mu) * rstd * g1.z + e1.z;
    r[7] = (v[7] - mu) * rstd * g1.w + e1.w;

    uint4 w;
    w.x = (unsigned)bfb(r[0]) | ((unsigned)bfb(r[1]) << 16);
    w.y = (unsigned)bfb(r[2]) | ((unsigned)bfb(r[3]) << 16);
    w.z = (unsigned)bfb(r[4]) | ((unsigned)bfb(r[5]) << 16);
    w.w = (unsigned)bfb(r[6]) | ((unsigned)bfb(r[7]) << 16);
    *(uint4*)&outb[(size_t)row * 512 + c] = w;
}

// ------------------------------------------------------------------
// out fp32 = LayerNorm(h1b bf16 + f2b bf16)
// ------------------------------------------------------------------
__global__ __launch_bounds__(256) void add_ln_from_bf16(
    const bf16* __restrict__ Xb, const bf16* __restrict__ Yb,
    const float* __restrict__ gamma, const float* __restrict__ beta,
    float* __restrict__ out)
{
    const int wave = threadIdx.x >> 6;
    const int lane = threadIdx.x & 63;
    const int row = blockIdx.x * 4 + wave;
    const bf16x8 xv = *(const bf16x8*)&Xb[(size_t)row * 512 + lane * 8];
    const bf16x8 yv = *(const bf16x8*)&Yb[(size_t)row * 512 + lane * 8];

    float v[8];
    #pragma unroll
    for (int i = 0; i < 8; ++i) v[i] = (float)xv[i] + (float)yv[i];

    float s = 0.f, sq = 0.f;
    #pragma unroll
    for (int i = 0; i < 8; ++i) { s += v[i]; sq += v[i] * v[i]; }
    #pragma unroll
    for (int off = 1; off < 64; off <<= 1) {
        s += __shfl_xor(s, off, 64);
        sq += __shfl_xor(sq, off, 64);
    }
    const float mu = s * (1.f / 512.f);
    const float var = sq * (1.f / 512.f) - mu * mu;
    const float rstd = rsqrtf(var + EPS);

    const int c = lane * 8;
    const float4 g0 = *(const float4*)&gamma[c];
    const float4 g1 = *(const float4*)&gamma[c + 4];
    const float4 e0 = *(const float4*)&beta[c];
    const float4 e1 = *(const float4*)&beta[c + 4];
    float4 r0, r1;
    r0.x = (v[0] - mu) * rstd * g0.x + e0.x;
    r0.y = (v[1] - mu) * rstd * g0.y + e0.y;
    r0.z = (v[2] - mu) * rstd * g0.z + e0.z;
    r0.w = (v[3] - mu) * rstd * g0.w + e0.w;
    r1.x = (v[4] - mu) * rstd * g1.x + e1.x;
    r1.y = (v[5] - mu) * rstd * g1.y + e1.y;
    r1.z = (v[6] - mu) * rstd * g1.z + e1.z;
    r1.w = (v[7] - mu) * rstd * g1.w + e1.w;
    float* op = out + (size_t)row * 512 + c;
    *(float4*)op = r0;
    *(float4*)(op + 4) = r1;
}

// ------------------------------------------------------------------
extern "C" void kernel_launch(void* const* d_in, const int* in_sizes, int n_in,
                              void* d_out, int out_size, void* d_ws, size_t ws_size,
                              hipStream_t stream)
{
    const float* h    = (const float*)d_in[0];
    const float* ab   = (const float*)d_in[1];
    const int*   mask = (const int*)d_in[2];
    const float* Wqkv = (const float*)d_in[3];
    const float* bqkv = (const float*)d_in[4];
    const float* Wo   = (const float*)d_in[5];
    const float* bo   = (const float*)d_in[6];
    const float* W1   = (const float*)d_in[7];
    const float* b1   = (const float*)d_in[8];
    const float* W2   = (const float*)d_in[9];
    const float* b2   = (const float*)d_in[10];
    const float* g1   = (const float*)d_in[11];
    const float* be1  = (const float*)d_in[12];
    const float* g2   = (const float*)d_in[13];
    const float* be2  = (const float*)d_in[14];
    float* out = (float*)d_out;
    char* ws = (char*)d_ws;

    const int M = 8 * 1024;
    const size_t MB = 1024 * 1024;

    bf16*  hb    = (bf16*)(ws + 0 * MB);    // 8MB
    bf16*  Wtq   = (bf16*)(ws + 8 * MB);    // 1.5MB
    bf16*  Wto   = (bf16*)(ws + 10 * MB);   // 0.5MB
    bf16*  Wt1   = (bf16*)(ws + 11 * MB);   // 2MB
    bf16*  Wt2   = (bf16*)(ws + 13 * MB);   // 2MB
    bf16*  Qb    = (bf16*)(ws + 15 * MB);   // 8MB
    bf16*  Kb    = (bf16*)(ws + 23 * MB);   // 8MB
    bf16*  Vtb   = (bf16*)(ws + 31 * MB);   // 8MB
    bf16*  aob   = (bf16*)(ws + 39 * MB);   // 8MB
    bf16*  projb = (bf16*)(ws + 47 * MB);   // 8MB
    bf16*  h1b   = (bf16*)(ws + 55 * MB);   // 8MB
    bf16*  ffb   = (bf16*)(ws + 63 * MB);   // 32MB
    bf16*  f2b   = (bf16*)(ws + 95 * MB);   // 8MB

    prep_kernel<<<dim3(5120), 256, 0, stream>>>(h, Wqkv, Wo, W1, W2, hb, Wtq, Wto, Wt1, Wt2);
    gemm_qkv<<<dim3(M / 128, 1536 / 128), 256, 0, stream>>>(hb, Wtq, bqkv, Qb, Kb, Vtb, M, 1536, 512);
    // 8-wave blocks, zero-tail grid: 64 x 8 = 512 blocks @ 2/CU
    attn_mfma<<<dim3(64, SEQ_L / 128), 512, 0, stream>>>(Qb, Kb, Vtb, ab, mask, aob);
    gemm_bf16<<<dim3(M / 128, 512 / 128), 256, 0, stream>>>(aob, Wto, bo, projb, M, 512, 512, 0);
    add_ln_to_bf16<<<dim3(M / 4), 256, 0, stream>>>(h, projb, g1, be1, h1b);
    gemm_bf16<<<dim3(M / 128, 2048 / 128), 256, 0, stream>>>(h1b, Wt1, b1, ffb, M, 2048, 512, 1);
    gemm_bf16<<<dim3(M / 128, 512 / 128), 256, 0, stream>>>(ffb, Wt2, b2, f2b, M, 512, 2048, 0);
    add_ln_from_bf16<<<dim3(M / 4), 256, 0, stream>>>(h1b, f2b, g2, be2, out);
}

// Round 15
// 221.804 us; speedup vs baseline: 1.0791x; 1.0224x over previous
//
#include <hip/hip_runtime.h>
#include <hip/hip_bf16.h>
#include <math.h>

#define NUM_HEADS 8
#define SEQ_L 1024
#define EPS 1e-5f
#define LOG2E 1.44269504088896f
#define KVB 128

typedef __bf16 bf16x8 __attribute__((ext_vector_type(8)));
typedef float f32x4 __attribute__((ext_vector_type(4)));
typedef __hip_bfloat16 bf16;

#define AS1 __attribute__((address_space(1)))
#define AS3 __attribute__((address_space(3)))

__device__ __forceinline__ void gload_lds16(const void* g, void* l) {
    __builtin_amdgcn_global_load_lds((const AS1 unsigned*)g, (AS3 unsigned*)l, 16, 0, 0);
}

__device__ __forceinline__ unsigned short bfb(float x) {
    bf16 b = __float2bfloat16(x);
    return *(unsigned short*)&b;
}

// XOR swizzle for [R][64] bf16 LDS tiles: elem ^= ((row&7)<<3) (16B granules)
__device__ __forceinline__ int swz(int el, int row) { return el ^ ((row & 7) << 3); }

// ------------------------------------------------------------------
// Fused prep: h fp32->bf16 copy + 4 weight transposes (fp32->bf16).
// ------------------------------------------------------------------
__global__ __launch_bounds__(256) void prep_kernel(
    const float* __restrict__ h, const float* __restrict__ Wqkv,
    const float* __restrict__ Wo, const float* __restrict__ W1,
    const float* __restrict__ W2,
    bf16* __restrict__ hb, bf16* __restrict__ Wtq, bf16* __restrict__ Wto,
    bf16* __restrict__ Wt1, bf16* __restrict__ Wt2)
{
    const int bid = blockIdx.x;
    const int tid = threadIdx.x;
    if (bid < 2048) {
        const int i = (bid * 256 + tid) * 8;
        const float4 v0 = *(const float4*)&h[i];
        const float4 v1 = *(const float4*)&h[i + 4];
        uint4 w;
        w.x = (unsigned)bfb(v0.x) | ((unsigned)bfb(v0.y) << 16);
        w.y = (unsigned)bfb(v0.z) | ((unsigned)bfb(v0.w) << 16);
        w.z = (unsigned)bfb(v1.x) | ((unsigned)bfb(v1.y) << 16);
        w.w = (unsigned)bfb(v1.z) | ((unsigned)bfb(v1.w) << 16);
        *(uint4*)&hb[i] = w;
        return;
    }
    int r = bid - 2048;
    const float* W; bf16* Wt; int K, N, bx, by;
    if (r < 768)        { W = Wqkv; Wt = Wtq; K = 512;  N = 1536; bx = r % 48; by = r / 48; }
    else if (r < 1024)  { r -= 768;  W = Wo; Wt = Wto; K = 512;  N = 512;  bx = r % 16; by = r / 16; }
    else if (r < 2048)  { r -= 1024; W = W1; Wt = Wt1; K = 512;  N = 2048; bx = r % 64; by = r / 64; }
    else                { r -= 2048; W = W2; Wt = Wt2; K = 2048; N = 512;  bx = r % 16; by = r / 16; }

    __shared__ float t[32][33];
    const int tx = tid & 31, ty = tid >> 5;
    const int n0 = bx * 32, k0 = by * 32;
    #pragma unroll
    for (int q = 0; q < 4; ++q)
        t[ty + 8 * q][tx] = W[(size_t)(k0 + ty + 8 * q) * N + n0 + tx];
    __syncthreads();
    #pragma unroll
    for (int q = 0; q < 4; ++q)
        Wt[(size_t)(n0 + ty + 8 * q) * K + k0 + tx] = __float2bfloat16(t[tx][ty + 8 * q]);
}

// ------------------------------------------------------------------
// bf16 MFMA GEMM, BK=64 (half the barriers of BK=32):
// Cb[M,N] = bf16(A @ Bt^T + bias), optional relu.
// LDS [128][64] per operand, granule-swizzled (g ^= row&7) via
// pre-swizzled global source + swizzled fragment reads (rule 21).
// Grid transposed for XCD L2 locality (blockIdx.x = M-tile).
// ------------------------------------------------------------------
__global__ __launch_bounds__(256) void gemm_bf16(
    const bf16* __restrict__ A, const bf16* __restrict__ Bt,
    const float* __restrict__ bias, bf16* __restrict__ Cb,
    int M, int N, int K, int relu)
{
    __shared__ __align__(16) bf16 Abuf[128 * 64];   // 16KB
    __shared__ __align__(16) bf16 Bbuf[128 * 64];   // 16KB
    const int tid = threadIdx.x;
    const int wv = tid >> 6, lane = tid & 63;
    const int row0 = blockIdx.x * 128, col0 = blockIdx.y * 128;
    const int wm = (wv >> 1) * 64, wn = (wv & 1) * 64;
    const int r0 = lane & 15, kb = lane >> 4;

    f32x4 acc[4][4] = {};

    for (int k0 = 0; k0 < K; k0 += 64) {
        #pragma unroll
        for (int it = 0; it < 4; ++it) {
            const int ch = it * 256 + wv * 64 + lane;   // 0..1023
            const int row = ch >> 3, g = ch & 7;
            const int gp = g ^ (row & 7);               // pre-swizzled source granule
            gload_lds16(&A[(size_t)(row0 + row) * K + k0 + gp * 8],
                        &Abuf[(it * 256 + wv * 64) * 8]);
            gload_lds16(&Bt[(size_t)(col0 + row) * K + k0 + gp * 8],
                        &Bbuf[(it * 256 + wv * 64) * 8]);
        }
        __syncthreads();

        bf16x8 a[4][2], b[4][2];
        #pragma unroll
        for (int i = 0; i < 4; ++i) {
            const int row = wm + i * 16 + r0;
            #pragma unroll
            for (int k2 = 0; k2 < 2; ++k2)
                a[i][k2] = *(const bf16x8*)&Abuf[row * 64 + ((kb + k2 * 4) ^ (row & 7)) * 8];
        }
        #pragma unroll
        for (int j = 0; j < 4; ++j) {
            const int row = wn + j * 16 + r0;
            #pragma unroll
            for (int k2 = 0; k2 < 2; ++k2)
                b[j][k2] = *(const bf16x8*)&Bbuf[row * 64 + ((kb + k2 * 4) ^ (row & 7)) * 8];
        }
        #pragma unroll
        for (int k2 = 0; k2 < 2; ++k2)
            #pragma unroll
            for (int i = 0; i < 4; ++i)
                #pragma unroll
                for (int j = 0; j < 4; ++j)
                    acc[i][j] = __builtin_amdgcn_mfma_f32_16x16x32_bf16(a[i][k2], b[j][k2], acc[i][j], 0, 0, 0);
        __syncthreads();
    }

    float bv[4];
    #pragma unroll
    for (int j = 0; j < 4; ++j) bv[j] = bias[col0 + wn + j * 16 + r0];

    #pragma unroll
    for (int i = 0; i < 4; ++i) {
        #pragma unroll
        for (int j = 0; j < 4; ++j) {
            const int col = col0 + wn + j * 16 + r0;
            #pragma unroll
            for (int reg = 0; reg < 4; ++reg) {
                const int row = row0 + wm + i * 16 + kb * 4 + reg;
                float v = acc[i][j][reg] + bv[j];
                if (relu) v = fmaxf(v, 0.f);
                Cb[(size_t)row * N + col] = __float2bfloat16(v);
            }
        }
    }
}

// ------------------------------------------------------------------
// QKV GEMM, BK=64 (same structure) with split epilogue -> Qb/Kb/Vtb.
// ------------------------------------------------------------------
__global__ __launch_bounds__(256) void gemm_qkv(
    const bf16* __restrict__ A, const bf16* __restrict__ Bt,
    const float* __restrict__ bias,
    bf16* __restrict__ Qb, bf16* __restrict__ Kb, bf16* __restrict__ Vtb,
    int M, int N, int K)
{
    __shared__ __align__(16) bf16 Abuf[128 * 64];
    __shared__ __align__(16) bf16 Bbuf[128 * 64];
    const int tid = threadIdx.x;
    const int wv = tid >> 6, lane = tid & 63;
    const int row0 = blockIdx.x * 128, col0 = blockIdx.y * 128;
    const int wm = (wv >> 1) * 64, wn = (wv & 1) * 64;
    const int r0 = lane & 15, kb = lane >> 4;

    f32x4 acc[4][4] = {};

    for (int k0 = 0; k0 < K; k0 += 64) {
        #pragma unroll
        for (int it = 0; it < 4; ++it) {
            const int ch = it * 256 + wv * 64 + lane;
            const int row = ch >> 3, g = ch & 7;
            const int gp = g ^ (row & 7);
            gload_lds16(&A[(size_t)(row0 + row) * K + k0 + gp * 8],
                        &Abuf[(it * 256 + wv * 64) * 8]);
            gload_lds16(&Bt[(size_t)(col0 + row) * K + k0 + gp * 8],
                        &Bbuf[(it * 256 + wv * 64) * 8]);
        }
        __syncthreads();

        bf16x8 a[4][2], b[4][2];
        #pragma unroll
        for (int i = 0; i < 4; ++i) {
            const int row = wm + i * 16 + r0;
            #pragma unroll
            for (int k2 = 0; k2 < 2; ++k2)
                a[i][k2] = *(const bf16x8*)&Abuf[row * 64 + ((kb + k2 * 4) ^ (row & 7)) * 8];
        }
        #pragma unroll
        for (int j = 0; j < 4; ++j) {
            const int row = wn + j * 16 + r0;
            #pragma unroll
            for (int k2 = 0; k2 < 2; ++k2)
                b[j][k2] = *(const bf16x8*)&Bbuf[row * 64 + ((kb + k2 * 4) ^ (row & 7)) * 8];
        }
        #pragma unroll
        for (int k2 = 0; k2 < 2; ++k2)
            #pragma unroll
            for (int i = 0; i < 4; ++i)
                #pragma unroll
                for (int j = 0; j < 4; ++j)
                    acc[i][j] = __builtin_amdgcn_mfma_f32_16x16x32_bf16(a[i][k2], b[j][k2], acc[i][j], 0, 0, 0);
        __syncthreads();
    }

    #pragma unroll
    for (int i = 0; i < 4; ++i) {
        #pragma unroll
        for (int j = 0; j < 4; ++j) {
            const int col = col0 + wn + j * 16 + r0;     // 0..1535
            const float bv = bias[col];
            const int region = col >> 9;                  // 0=q 1=k 2=v
            const int cc = col & 511;
            const int head = cc >> 6, d = cc & 63;
            const int l0 = row0 + wm + i * 16 + kb * 4;
            const int b_ = l0 >> 10, l_ = l0 & 1023;
            if (region == 2) {
                unsigned short pk[4];
                #pragma unroll
                for (int reg = 0; reg < 4; ++reg) pk[reg] = bfb(acc[i][j][reg] + bv);
                *(ushort4*)&Vtb[((size_t)(b_ * NUM_HEADS + head) * 64 + d) * SEQ_L + l_] =
                    make_ushort4(pk[0], pk[1], pk[2], pk[3]);
            } else {
                const float s = (region == 0) ? (0.125f * LOG2E) : 1.0f;
                bf16* dst = (region == 0) ? Qb : Kb;
                #pragma unroll
                for (int reg = 0; reg < 4; ++reg) {
                    dst[((size_t)(b_ * NUM_HEADS + head) * SEQ_L + l_ + reg) * 64 + d] =
                        __float2bfloat16((acc[i][j][reg] + bv) * s);
                }
            }
        }
    }
}

// ------------------------------------------------------------------
// MFMA flash attention — 8-wave/512-thread blocks (r14, best measured).
// ------------------------------------------------------------------
__global__ __launch_bounds__(512) void attn_mfma(
    const bf16* __restrict__ Qb, const bf16* __restrict__ Kb,
    const bf16* __restrict__ Vtb, const float* __restrict__ abias,
    const int* __restrict__ mask, bf16* __restrict__ out)
{
    const int bh = blockIdx.x;               // 0..63  (XCD = bh%8)
    const int b = bh >> 3, h = bh & 7;
    const int q0 = blockIdx.y * 128;
    const int tid = threadIdx.x;
    const int wv = tid >> 6, lane = tid & 63; // wv 0..7
    const int ql = lane & 15;
    const int hi = lane >> 4;

    __shared__ __align__(16) bf16 Ks[KVB * 64];      // 16KB [key][d] swizzled
    __shared__ __align__(16) bf16 Vs[64 * KVB];      // 16KB [d][key] swizzled
    __shared__ __align__(16) bf16 Ps[8][16 * KVB];   // 32KB per-wave P tiles

    const bf16* Kbase = Kb + (size_t)bh * SEQ_L * 64;
    const bf16* Vbase = Vtb + (size_t)bh * 64 * SEQ_L;
    const int* mbase = mask + b * SEQ_L;

    auto stageKV = [&](int k0) {
        #pragma unroll
        for (int it = 0; it < 2; ++it) {
            const int blk = wv * 2 + it;
            const int row = blk * 8 + (lane >> 3);
            const int gp = (lane & 7) ^ (row & 7);
            gload_lds16(&Kbase[(size_t)(k0 + row) * 64 + gp * 8],
                        &Ks[blk * 512]);
        }
        #pragma unroll
        for (int it = 0; it < 2; ++it) {
            const int blk = wv * 2 + it;
            const int row = blk * 4 + (lane >> 4);
            const int g = lane & 15;
            const int gp = (g & 8) | ((g & 7) ^ (row & 7));
            gload_lds16(&Vbase[(size_t)row * SEQ_L + k0 + gp * 8],
                        &Vs[blk * 512]);
        }
    };

    const int qrow = q0 + wv * 16 + ql;
    bf16x8 qf[2];
    #pragma unroll
    for (int kk = 0; kk < 2; ++kk)
        qf[kk] = *(const bf16x8*)&Qb[((size_t)bh * SEQ_L + qrow) * 64 + kk * 32 + hi * 8];

    const size_t bias_row = ((size_t)(b * NUM_HEADS + h) * SEQ_L + qrow) * SEQ_L;

    f32x4 breg[8];
    auto loadBias = [&](int k0) {
        #pragma unroll
        for (int c = 0; c < 8; ++c)
            breg[c] = *(const f32x4*)&abias[bias_row + k0 + c * 16 + hi * 4];
    };
    int4 mfr[8];
    auto loadMask = [&](int k0) {
        #pragma unroll
        for (int c = 0; c < 8; ++c)
            mfr[c] = *(const int4*)&mbase[k0 + c * 16 + hi * 4];
    };

    f32x4 o[4] = {};
    float m = -1e30f, l = 0.f;

    stageKV(0);
    loadBias(0);
    loadMask(0);
    __syncthreads();

    for (int t = 0; t < 8; ++t) {
        f32x4 p[8];
        #pragma unroll
        for (int c = 0; c < 8; ++c) {
            p[c][0] = (mfr[c].x > 0) ? breg[c][0] * LOG2E : -1e30f;
            p[c][1] = (mfr[c].y > 0) ? breg[c][1] * LOG2E : -1e30f;
            p[c][2] = (mfr[c].z > 0) ? breg[c][2] * LOG2E : -1e30f;
            p[c][3] = (mfr[c].w > 0) ? breg[c][3] * LOG2E : -1e30f;
        }

        if (t < 7) { loadBias((t + 1) * KVB); loadMask((t + 1) * KVB); }

        __builtin_amdgcn_s_setprio(1);
        #pragma unroll
        for (int c = 0; c < 8; ++c) {
            const int row = c * 16 + ql;
            #pragma unroll
            for (int kk = 0; kk < 2; ++kk) {
                const bf16x8 kf = *(const bf16x8*)&Ks[swz(row * 64 + kk * 32 + hi * 8, row)];
                p[c] = __builtin_amdgcn_mfma_f32_16x16x32_bf16(kf, qf[kk], p[c], 0, 0, 0);
            }
        }
        __builtin_amdgcn_s_setprio(0);

        float mx = p[0][0];
        #pragma unroll
        for (int c = 0; c < 8; ++c)
            #pragma unroll
            for (int reg = 0; reg < 4; ++reg) mx = fmaxf(mx, p[c][reg]);
        mx = fmaxf(mx, __shfl_xor(mx, 16, 64));
        mx = fmaxf(mx, __shfl_xor(mx, 32, 64));

        if (!__all(mx <= m + 11.0f)) {
            const float mnew = fmaxf(m, mx);
            const float scale = __builtin_exp2f(m - mnew);
            m = mnew;
            l *= scale;
            #pragma unroll
            for (int reg = 0; reg < 4; ++reg) {
                const float sc_q = __shfl(scale, (lane & 48) | (hi * 4 + reg), 64);
                #pragma unroll
                for (int c2 = 0; c2 < 4; ++c2) o[c2][reg] *= sc_q;
            }
        }

        float lsum = 0.f;
        #pragma unroll
        for (int c = 0; c < 8; ++c)
            #pragma unroll
            for (int reg = 0; reg < 4; ++reg) {
                const float pv = __builtin_exp2f(p[c][reg] - m);
                p[c][reg] = pv;
                lsum += pv;
            }
        l += lsum;

        #pragma unroll
        for (int c = 0; c < 8; ++c) {
            const int el = ql * KVB + c * 16 + hi * 4;
            uint2 pk;
            pk.x = (unsigned)bfb(p[c][0]) | ((unsigned)bfb(p[c][1]) << 16);
            pk.y = (unsigned)bfb(p[c][2]) | ((unsigned)bfb(p[c][3]) << 16);
            *(uint2*)&Ps[wv][swz(el, ql)] = pk;
        }

        __builtin_amdgcn_s_setprio(1);
        #pragma unroll
        for (int kk = 0; kk < 4; ++kk) {
            const bf16x8 pf = *(const bf16x8*)&Ps[wv][swz(ql * KVB + kk * 32 + hi * 8, ql)];
            #pragma unroll
            for (int c2 = 0; c2 < 4; ++c2) {
                const int vrow = c2 * 16 + ql;
                const bf16x8 vf = *(const bf16x8*)&Vs[swz(vrow * KVB + kk * 32 + hi * 8, vrow)];
                o[c2] = __builtin_amdgcn_mfma_f32_16x16x32_bf16(pf, vf, o[c2], 0, 0, 0);
            }
        }
        __builtin_amdgcn_s_setprio(0);

        if (t < 7) {
            __syncthreads();
            stageKV((t + 1) * KVB);
            __syncthreads();
        }
    }

    l += __shfl_xor(l, 16, 64);
    l += __shfl_xor(l, 32, 64);
    const float invl = (l > 0.f) ? (1.0f / l) : 0.f;
    #pragma unroll
    for (int reg = 0; reg < 4; ++reg) {
        const float inv_q = __shfl(invl, (lane & 48) | (hi * 4 + reg), 64);
        const int row = q0 + wv * 16 + hi * 4 + reg;
        #pragma unroll
        for (int c2 = 0; c2 < 4; ++c2)
            out[((size_t)(b * SEQ_L + row)) * 512 + h * 64 + c2 * 16 + ql] =
                __float2bfloat16(o[c2][reg] * inv_q);
    }
}

// ------------------------------------------------------------------
// h1b = bf16(LayerNorm(h fp32 + projb bf16))
// ------------------------------------------------------------------
__global__ __launch_bounds__(256) void add_ln_to_bf16(
    const float* __restrict__ X, const bf16* __restrict__ Yb,
    const float* __restrict__ gamma, const float* __restrict__ beta,
    bf16* __restrict__ outb)
{
    const int wave = threadIdx.x >> 6;
    const int lane = threadIdx.x & 63;
    const int row = blockIdx.x * 4 + wave;
    const float* xp = X + (size_t)row * 512 + lane * 8;
    const bf16x8 yv = *(const bf16x8*)&Yb[(size_t)row * 512 + lane * 8];

    float v[8];
    const float4 a0 = *(const float4*)xp;
    const float4 a1 = *(const float4*)(xp + 4);
    v[0] = a0.x + (float)yv[0]; v[1] = a0.y + (float)yv[1];
    v[2] = a0.z + (float)yv[2]; v[3] = a0.w + (float)yv[3];
    v[4] = a1.x + (float)yv[4]; v[5] = a1.y + (float)yv[5];
    v[6] = a1.z + (float)yv[6]; v[7] = a1.w + (float)yv[7];

    float s = 0.f, sq = 0.f;
    #pragma unroll
    for (int i = 0; i < 8; ++i) { s += v[i]; sq += v[i] * v[i]; }
    #pragma unroll
    for (int off = 1; off < 64; off <<= 1) {
        s += __shfl_xor(s, off, 64);
        sq += __shfl_xor(sq, off, 64);
    }
    const float mu = s * (1.f / 512.f);
    const float var = sq * (1.f / 512.f) - mu * mu;
    const float rstd = rsqrtf(var + EPS);

    const int c = lane * 8;
    const float4 g0 = *(const float4*)&gamma[c];
    const float4 g1 = *(const float4*)&gamma[c + 4];
    const float4 e0 = *(const float4*)&beta[c];
    const float4 e1 = *(const float4*)&beta[c + 4];
    float r[8];
    r[0] = (v[0] - mu) * rstd * g0.x + e0.x;
    r[1] = (v[1] - mu) * rstd * g0.y + e0.y;
    r[2] = (v[2] - mu) * rstd * g0.z + e0.z;
    r[3] = (v[3] - mu) * rstd * g0.w + e0.w;
    r[4] = (v[4] - mu) * rstd * g1.x + e1.x;
    r[5] = (v[5] - mu) * rstd * g1.y + e1.y;
    r[6] = (v[6] - mu) * rstd * g1.z + e1.z;
    r[7] = (v[7] - mu) * rstd * g1.w + e1.w;

    uint4 w;
    w.x = (unsigned)bfb(r[0]) | ((unsigned)bfb(r[1]) << 16);
    w.y = (unsigned)bfb(r[2]) | ((unsigned)bfb(r[3]) << 16);
    w.z = (unsigned)bfb(r[4]) | ((unsigned)bfb(r[5]) << 16);
    w.w = (unsigned)bfb(r[6]) | ((unsigned)bfb(r[7]) << 16);
    *(uint4*)&outb[(size_t)row * 512 + c] = w;
}

// ------------------------------------------------------------------
// out fp32 = LayerNorm(h1b bf16 + f2b bf16)
// ------------------------------------------------------------------
__global__ __launch_bounds__(256) void add_ln_from_bf16(
    const bf16* __restrict__ Xb, const bf16* __restrict__ Yb,
    const float* __restrict__ gamma, const float* __restrict__ beta,
    float* __restrict__ out)
{
    const int wave = threadIdx.x >> 6;
    const int lane = threadIdx.x & 63;
    const int row = blockIdx.x * 4 + wave;
    const bf16x8 xv = *(const bf16x8*)&Xb[(size_t)row * 512 + lane * 8];
    const bf16x8 yv = *(const bf16x8*)&Yb[(size_t)row * 512 + lane * 8];

    float v[8];
    #pragma unroll
    for (int i = 0; i < 8; ++i) v[i] = (float)xv[i] + (float)yv[i];

    float s = 0.f, sq = 0.f;
    #pragma unroll
    for (int i = 0; i < 8; ++i) { s += v[i]; sq += v[i] * v[i]; }
    #pragma unroll
    for (int off = 1; off < 64; off <<= 1) {
        s += __shfl_xor(s, off, 64);
        sq += __shfl_xor(sq, off, 64);
    }
    const float mu = s * (1.f / 512.f);
    const float var = sq * (1.f / 512.f) - mu * mu;
    const float rstd = rsqrtf(var + EPS);

    const int c = lane * 8;
    const float4 g0 = *(const float4*)&gamma[c];
    const float4 g1 = *(const float4*)&gamma[c + 4];
    const float4 e0 = *(const float4*)&beta[c];
    const float4 e1 = *(const float4*)&beta[c + 4];
    float4 r0, r1;
    r0.x = (v[0] - mu) * rstd * g0.x + e0.x;
    r0.y = (v[1] - mu) * rstd * g0.y + e0.y;
    r0.z = (v[2] - mu) * rstd * g0.z + e0.z;
    r0.w = (v[3] - mu) * rstd * g0.w + e0.w;
    r1.x = (v[4] - mu) * rstd * g1.x + e1.x;
    r1.y = (v[5] - mu) * rstd * g1.y + e1.y;
    r1.z = (v[6] - mu) * rstd * g1.z + e1.z;
    r1.w = (v[7] - mu) * rstd * g1.w + e1.w;
    float* op = out + (size_t)row * 512 + c;
    *(float4*)op = r0;
    *(float4*)(op + 4) = r1;
}

// ------------------------------------------------------------------
extern "C" void kernel_launch(void* const* d_in, const int* in_sizes, int n_in,
                              void* d_out, int out_size, void* d_ws, size_t ws_size,
                              hipStream_t stream)
{
    const float* h    = (const float*)d_in[0];
    const float* ab   = (const float*)d_in[1];
    const int*   mask = (const int*)d_in[2];
    const float* Wqkv = (const float*)d_in[3];
    const float* bqkv = (const float*)d_in[4];
    const float* Wo   = (const float*)d_in[5];
    const float* bo   = (const float*)d_in[6];
    const float* W1   = (const float*)d_in[7];
    const float* b1   = (const float*)d_in[8];
    const float* W2   = (const float*)d_in[9];
    const float* b2   = (const float*)d_in[10];
    const float* g1   = (const float*)d_in[11];
    const float* be1  = (const float*)d_in[12];
    const float* g2   = (const float*)d_in[13];
    const float* be2  = (const float*)d_in[14];
    float* out = (float*)d_out;
    char* ws = (char*)d_ws;

    const int M = 8 * 1024;
    const size_t MB = 1024 * 1024;

    bf16*  hb    = (bf16*)(ws + 0 * MB);    // 8MB
    bf16*  Wtq   = (bf16*)(ws + 8 * MB);    // 1.5MB
    bf16*  Wto   = (bf16*)(ws + 10 * MB);   // 0.5MB
    bf16*  Wt1   = (bf16*)(ws + 11 * MB);   // 2MB
    bf16*  Wt2   = (bf16*)(ws + 13 * MB);   // 2MB
    bf16*  Qb    = (bf16*)(ws + 15 * MB);   // 8MB
    bf16*  Kb    = (bf16*)(ws + 23 * MB);   // 8MB
    bf16*  Vtb   = (bf16*)(ws + 31 * MB);   // 8MB
    bf16*  aob   = (bf16*)(ws + 39 * MB);   // 8MB
    bf16*  projb = (bf16*)(ws + 47 * MB);   // 8MB
    bf16*  h1b   = (bf16*)(ws + 55 * MB);   // 8MB
    bf16*  ffb   = (bf16*)(ws + 63 * MB);   // 32MB
    bf16*  f2b   = (bf16*)(ws + 95 * MB);   // 8MB

    prep_kernel<<<dim3(5120), 256, 0, stream>>>(h, Wqkv, Wo, W1, W2, hb, Wtq, Wto, Wt1, Wt2);
    gemm_qkv<<<dim3(M / 128, 1536 / 128), 256, 0, stream>>>(hb, Wtq, bqkv, Qb, Kb, Vtb, M, 1536, 512);
    attn_mfma<<<dim3(64, SEQ_L / 128), 512, 0, stream>>>(Qb, Kb, Vtb, ab, mask, aob);
    gemm_bf16<<<dim3(M / 128, 512 / 128), 256, 0, stream>>>(aob, Wto, bo, projb, M, 512, 512, 0);
    add_ln_to_bf16<<<dim3(M / 4), 256, 0, stream>>>(h, projb, g1, be1, h1b);
    gemm_bf16<<<dim3(M / 128, 2048 / 128), 256, 0, stream>>>(h1b, Wt1, b1, ffb, M, 2048, 512, 1);
    gemm_bf16<<<dim3(M / 128, 512 / 128), 256, 0, stream>>>(ffb, Wt2, b2, f2b, M, 512, 2048, 0);
    add_ln_from_bf16<<<dim3(M / 4), 256, 0, stream>>>(h1b, f2b, g2, be2, out);
}

// Round 16
// 211.957 us; speedup vs baseline: 1.1292x; 1.0465x over previous
//
#include <hip/hip_runtime.h>
#include <hip/hip_bf16.h>
#include <math.h>

#define NUM_HEADS 8
#define SEQ_L 1024
#define EPS 1e-5f
#define LOG2E 1.44269504088896f
#define KVB 128

typedef __bf16 bf16x8 __attribute__((ext_vector_type(8)));
typedef float f32x4 __attribute__((ext_vector_type(4)));
typedef __hip_bfloat16 bf16;

#define AS1 __attribute__((address_space(1)))
#define AS3 __attribute__((address_space(3)))

__device__ __forceinline__ void gload_lds16(const void* g, void* l) {
    __builtin_amdgcn_global_load_lds((const AS1 unsigned*)g, (AS3 unsigned*)l, 16, 0, 0);
}

__device__ __forceinline__ unsigned short bfb(float x) {
    bf16 b = __float2bfloat16(x);
    return *(unsigned short*)&b;
}

// XOR swizzle for [R][64] bf16 LDS tiles: elem ^= ((row&7)<<3) (16B granules)
__device__ __forceinline__ int swz(int el, int row) { return el ^ ((row & 7) << 3); }

// ------------------------------------------------------------------
// Fused prep: h fp32->bf16 copy + 4 weight transposes (fp32->bf16).
// ------------------------------------------------------------------
__global__ __launch_bounds__(256) void prep_kernel(
    const float* __restrict__ h, const float* __restrict__ Wqkv,
    const float* __restrict__ Wo, const float* __restrict__ W1,
    const float* __restrict__ W2,
    bf16* __restrict__ hb, bf16* __restrict__ Wtq, bf16* __restrict__ Wto,
    bf16* __restrict__ Wt1, bf16* __restrict__ Wt2)
{
    const int bid = blockIdx.x;
    const int tid = threadIdx.x;
    if (bid < 2048) {
        const int i = (bid * 256 + tid) * 8;
        const float4 v0 = *(const float4*)&h[i];
        const float4 v1 = *(const float4*)&h[i + 4];
        uint4 w;
        w.x = (unsigned)bfb(v0.x) | ((unsigned)bfb(v0.y) << 16);
        w.y = (unsigned)bfb(v0.z) | ((unsigned)bfb(v0.w) << 16);
        w.z = (unsigned)bfb(v1.x) | ((unsigned)bfb(v1.y) << 16);
        w.w = (unsigned)bfb(v1.z) | ((unsigned)bfb(v1.w) << 16);
        *(uint4*)&hb[i] = w;
        return;
    }
    int r = bid - 2048;
    const float* W; bf16* Wt; int K, N, bx, by;
    if (r < 768)        { W = Wqkv; Wt = Wtq; K = 512;  N = 1536; bx = r % 48; by = r / 48; }
    else if (r < 1024)  { r -= 768;  W = Wo; Wt = Wto; K = 512;  N = 512;  bx = r % 16; by = r / 16; }
    else if (r < 2048)  { r -= 1024; W = W1; Wt = Wt1; K = 512;  N = 2048; bx = r % 64; by = r / 64; }
    else                { r -= 2048; W = W2; Wt = Wt2; K = 2048; N = 512;  bx = r % 16; by = r / 16; }

    __shared__ float t[32][33];
    const int tx = tid & 31, ty = tid >> 5;
    const int n0 = bx * 32, k0 = by * 32;
    #pragma unroll
    for (int q = 0; q < 4; ++q)
        t[ty + 8 * q][tx] = W[(size_t)(k0 + ty + 8 * q) * N + n0 + tx];
    __syncthreads();
    #pragma unroll
    for (int q = 0; q < 4; ++q)
        Wt[(size_t)(n0 + ty + 8 * q) * K + k0 + tx] = __float2bfloat16(t[tx][ty + 8 * q]);
}

// ------------------------------------------------------------------
// bf16 MFMA GEMM, BK=64, LDS-transposed vectorized epilogue.
// Cb[M,N] = bf16(A @ Bt^T + bias), optional relu.
// smem (32KB) = staging (2x 128x64) unioned with C-transpose (128x128).
// ------------------------------------------------------------------
__global__ __launch_bounds__(256) void gemm_bf16(
    const bf16* __restrict__ A, const bf16* __restrict__ Bt,
    const float* __restrict__ bias, bf16* __restrict__ Cb,
    int M, int N, int K, int relu)
{
    __shared__ __align__(16) bf16 smem[16384];   // 32KB
    bf16* Abuf = smem;
    bf16* Bbuf = smem + 8192;
    const int tid = threadIdx.x;
    const int wv = tid >> 6, lane = tid & 63;
    const int row0 = blockIdx.x * 128, col0 = blockIdx.y * 128;
    const int wm = (wv >> 1) * 64, wn = (wv & 1) * 64;
    const int r0 = lane & 15, kb = lane >> 4;

    f32x4 acc[4][4] = {};

    for (int k0 = 0; k0 < K; k0 += 64) {
        #pragma unroll
        for (int it = 0; it < 4; ++it) {
            const int ch = it * 256 + wv * 64 + lane;   // 0..1023
            const int row = ch >> 3, g = ch & 7;
            const int gp = g ^ (row & 7);
            gload_lds16(&A[(size_t)(row0 + row) * K + k0 + gp * 8],
                        &Abuf[(it * 256 + wv * 64) * 8]);
            gload_lds16(&Bt[(size_t)(col0 + row) * K + k0 + gp * 8],
                        &Bbuf[(it * 256 + wv * 64) * 8]);
        }
        __syncthreads();

        bf16x8 a[4][2], b[4][2];
        #pragma unroll
        for (int i = 0; i < 4; ++i) {
            const int row = wm + i * 16 + r0;
            #pragma unroll
            for (int k2 = 0; k2 < 2; ++k2)
                a[i][k2] = *(const bf16x8*)&Abuf[row * 64 + ((kb + k2 * 4) ^ (row & 7)) * 8];
        }
        #pragma unroll
        for (int j = 0; j < 4; ++j) {
            const int row = wn + j * 16 + r0;
            #pragma unroll
            for (int k2 = 0; k2 < 2; ++k2)
                b[j][k2] = *(const bf16x8*)&Bbuf[row * 64 + ((kb + k2 * 4) ^ (row & 7)) * 8];
        }
        #pragma unroll
        for (int k2 = 0; k2 < 2; ++k2)
            #pragma unroll
            for (int i = 0; i < 4; ++i)
                #pragma unroll
                for (int j = 0; j < 4; ++j)
                    acc[i][j] = __builtin_amdgcn_mfma_f32_16x16x32_bf16(a[i][k2], b[j][k2], acc[i][j], 0, 0, 0);
        __syncthreads();
    }

    // epilogue: bias(+relu) -> bf16 -> smem[128][128] -> coalesced stores
    float bv[4];
    #pragma unroll
    for (int j = 0; j < 4; ++j) bv[j] = bias[col0 + wn + j * 16 + r0];

    #pragma unroll
    for (int i = 0; i < 4; ++i)
        #pragma unroll
        for (int j = 0; j < 4; ++j)
            #pragma unroll
            for (int reg = 0; reg < 4; ++reg) {
                float v = acc[i][j][reg] + bv[j];
                if (relu) v = fmaxf(v, 0.f);
                smem[(wm + i * 16 + kb * 4 + reg) * 128 + wn + j * 16 + r0] = __float2bfloat16(v);
            }
    __syncthreads();
    #pragma unroll
    for (int p = 0; p < 8; ++p) {
        const int row = p * 16 + (tid >> 4);
        const int c8 = (tid & 15) * 8;
        *(uint4*)&Cb[(size_t)(row0 + row) * N + col0 + c8] = *(const uint4*)&smem[row * 128 + c8];
    }
}

// ------------------------------------------------------------------
// QKV GEMM, BK=64, LDS-transposed epilogue -> Qb/Kb/Vtb (region
// uniform per block: col0 selects q/k/v).
// ------------------------------------------------------------------
__global__ __launch_bounds__(256) void gemm_qkv(
    const bf16* __restrict__ A, const bf16* __restrict__ Bt,
    const float* __restrict__ bias,
    bf16* __restrict__ Qb, bf16* __restrict__ Kb, bf16* __restrict__ Vtb,
    int M, int N, int K)
{
    __shared__ __align__(16) bf16 smem[16384];
    bf16* Abuf = smem;
    bf16* Bbuf = smem + 8192;
    const int tid = threadIdx.x;
    const int wv = tid >> 6, lane = tid & 63;
    const int row0 = blockIdx.x * 128, col0 = blockIdx.y * 128;
    const int wm = (wv >> 1) * 64, wn = (wv & 1) * 64;
    const int r0 = lane & 15, kb = lane >> 4;

    f32x4 acc[4][4] = {};

    for (int k0 = 0; k0 < K; k0 += 64) {
        #pragma unroll
        for (int it = 0; it < 4; ++it) {
            const int ch = it * 256 + wv * 64 + lane;
            const int row = ch >> 3, g = ch & 7;
            const int gp = g ^ (row & 7);
            gload_lds16(&A[(size_t)(row0 + row) * K + k0 + gp * 8],
                        &Abuf[(it * 256 + wv * 64) * 8]);
            gload_lds16(&Bt[(size_t)(col0 + row) * K + k0 + gp * 8],
                        &Bbuf[(it * 256 + wv * 64) * 8]);
        }
        __syncthreads();

        bf16x8 a[4][2], b[4][2];
        #pragma unroll
        for (int i = 0; i < 4; ++i) {
            const int row = wm + i * 16 + r0;
            #pragma unroll
            for (int k2 = 0; k2 < 2; ++k2)
                a[i][k2] = *(const bf16x8*)&Abuf[row * 64 + ((kb + k2 * 4) ^ (row & 7)) * 8];
        }
        #pragma unroll
        for (int j = 0; j < 4; ++j) {
            const int row = wn + j * 16 + r0;
            #pragma unroll
            for (int k2 = 0; k2 < 2; ++k2)
                b[j][k2] = *(const bf16x8*)&Bbuf[row * 64 + ((kb + k2 * 4) ^ (row & 7)) * 8];
        }
        #pragma unroll
        for (int k2 = 0; k2 < 2; ++k2)
            #pragma unroll
            for (int i = 0; i < 4; ++i)
                #pragma unroll
                for (int j = 0; j < 4; ++j)
                    acc[i][j] = __builtin_amdgcn_mfma_f32_16x16x32_bf16(a[i][k2], b[j][k2], acc[i][j], 0, 0, 0);
        __syncthreads();
    }

    const int region = col0 >> 9;                 // 0=q 1=k 2=v (uniform)
    const float s = (region == 0) ? (0.125f * LOG2E) : 1.0f;

    float bv[4];
    #pragma unroll
    for (int j = 0; j < 4; ++j) bv[j] = bias[col0 + wn + j * 16 + r0];

    #pragma unroll
    for (int i = 0; i < 4; ++i)
        #pragma unroll
        for (int j = 0; j < 4; ++j)
            #pragma unroll
            for (int reg = 0; reg < 4; ++reg)
                smem[(wm + i * 16 + kb * 4 + reg) * 128 + wn + j * 16 + r0] =
                    __float2bfloat16((acc[i][j][reg] + bv[j]) * s);
    __syncthreads();

    const int cbase = col0 & 511;                 // multiple of 64 within region
    if (region < 2) {
        bf16* dst = (region == 0) ? Qb : Kb;
        #pragma unroll
        for (int p = 0; p < 8; ++p) {
            const int lrow = p * 16 + (tid >> 4);
            const int c = (tid & 15) * 8;
            const int grow = row0 + lrow;
            const int b_ = grow >> 10, l_ = grow & 1023;
            const int head = (cbase + c) >> 6, d = c & 63;
            *(uint4*)&dst[((size_t)(b_ * NUM_HEADS + head) * SEQ_L + l_) * 64 + d] =
                *(const uint4*)&smem[lrow * 128 + c];
        }
    } else {
        // V: transposed read from smem, contiguous-in-l stores
        #pragma unroll
        for (int p = 0; p < 8; ++p) {
            const int dloc = p * 16 + (tid >> 4);       // 0..127
            const int l8 = (tid & 15) * 8;
            unsigned pk[4];
            #pragma unroll
            for (int e = 0; e < 4; ++e) {
                const unsigned short lo = *(const unsigned short*)&smem[(l8 + 2 * e) * 128 + dloc];
                const unsigned short hi2 = *(const unsigned short*)&smem[(l8 + 2 * e + 1) * 128 + dloc];
                pk[e] = (unsigned)lo | ((unsigned)hi2 << 16);
            }
            const int grow = row0 + l8;
            const int b_ = grow >> 10, l_ = grow & 1023;
            const int head = (cbase + dloc) >> 6, d = dloc & 63;
            uint4 w; w.x = pk[0]; w.y = pk[1]; w.z = pk[2]; w.w = pk[3];
            *(uint4*)&Vtb[((size_t)(b_ * NUM_HEADS + head) * 64 + d) * SEQ_L + l_] = w;
        }
    }
}

// ------------------------------------------------------------------
// MFMA flash attention — 8-wave/512-thread blocks (r14 structure),
// O-store via LDS (coalesced 128B rows).
// ------------------------------------------------------------------
__global__ __launch_bounds__(512) void attn_mfma(
    const bf16* __restrict__ Qb, const bf16* __restrict__ Kb,
    const bf16* __restrict__ Vtb, const float* __restrict__ abias,
    const int* __restrict__ mask, bf16* __restrict__ out)
{
    const int bh = blockIdx.x;               // 0..63  (XCD = bh%8)
    const int b = bh >> 3, h = bh & 7;
    const int q0 = blockIdx.y * 128;
    const int tid = threadIdx.x;
    const int wv = tid >> 6, lane = tid & 63; // wv 0..7
    const int ql = lane & 15;
    const int hi = lane >> 4;

    __shared__ __align__(16) bf16 Ks[KVB * 64];      // 16KB
    __shared__ __align__(16) bf16 Vs[64 * KVB];      // 16KB
    __shared__ __align__(16) bf16 Ps[8][16 * KVB];   // 32KB

    const bf16* Kbase = Kb + (size_t)bh * SEQ_L * 64;
    const bf16* Vbase = Vtb + (size_t)bh * 64 * SEQ_L;
    const int* mbase = mask + b * SEQ_L;

    auto stageKV = [&](int k0) {
        #pragma unroll
        for (int it = 0; it < 2; ++it) {
            const int blk = wv * 2 + it;
            const int row = blk * 8 + (lane >> 3);
            const int gp = (lane & 7) ^ (row & 7);
            gload_lds16(&Kbase[(size_t)(k0 + row) * 64 + gp * 8],
                        &Ks[blk * 512]);
        }
        #pragma unroll
        for (int it = 0; it < 2; ++it) {
            const int blk = wv * 2 + it;
            const int row = blk * 4 + (lane >> 4);
            const int g = lane & 15;
            const int gp = (g & 8) | ((g & 7) ^ (row & 7));
            gload_lds16(&Vbase[(size_t)row * SEQ_L + k0 + gp * 8],
                        &Vs[blk * 512]);
        }
    };

    const int qrow = q0 + wv * 16 + ql;
    bf16x8 qf[2];
    #pragma unroll
    for (int kk = 0; kk < 2; ++kk)
        qf[kk] = *(const bf16x8*)&Qb[((size_t)bh * SEQ_L + qrow) * 64 + kk * 32 + hi * 8];

    const size_t bias_row = ((size_t)(b * NUM_HEADS + h) * SEQ_L + qrow) * SEQ_L;

    f32x4 breg[8];
    auto loadBias = [&](int k0) {
        #pragma unroll
        for (int c = 0; c < 8; ++c)
            breg[c] = *(const f32x4*)&abias[bias_row + k0 + c * 16 + hi * 4];
    };
    int4 mfr[8];
    auto loadMask = [&](int k0) {
        #pragma unroll
        for (int c = 0; c < 8; ++c)
            mfr[c] = *(const int4*)&mbase[k0 + c * 16 + hi * 4];
    };

    f32x4 o[4] = {};
    float m = -1e30f, l = 0.f;

    stageKV(0);
    loadBias(0);
    loadMask(0);
    __syncthreads();

    for (int t = 0; t < 8; ++t) {
        f32x4 p[8];
        #pragma unroll
        for (int c = 0; c < 8; ++c) {
            p[c][0] = (mfr[c].x > 0) ? breg[c][0] * LOG2E : -1e30f;
            p[c][1] = (mfr[c].y > 0) ? breg[c][1] * LOG2E : -1e30f;
            p[c][2] = (mfr[c].z > 0) ? breg[c][2] * LOG2E : -1e30f;
            p[c][3] = (mfr[c].w > 0) ? breg[c][3] * LOG2E : -1e30f;
        }

        if (t < 7) { loadBias((t + 1) * KVB); loadMask((t + 1) * KVB); }

        __builtin_amdgcn_s_setprio(1);
        #pragma unroll
        for (int c = 0; c < 8; ++c) {
            const int row = c * 16 + ql;
            #pragma unroll
            for (int kk = 0; kk < 2; ++kk) {
                const bf16x8 kf = *(const bf16x8*)&Ks[swz(row * 64 + kk * 32 + hi * 8, row)];
                p[c] = __builtin_amdgcn_mfma_f32_16x16x32_bf16(kf, qf[kk], p[c], 0, 0, 0);
            }
        }
        __builtin_amdgcn_s_setprio(0);

        float mx = p[0][0];
        #pragma unroll
        for (int c = 0; c < 8; ++c)
            #pragma unroll
            for (int reg = 0; reg < 4; ++reg) mx = fmaxf(mx, p[c][reg]);
        mx = fmaxf(mx, __shfl_xor(mx, 16, 64));
        mx = fmaxf(mx, __shfl_xor(mx, 32, 64));

        if (!__all(mx <= m + 11.0f)) {
            const float mnew = fmaxf(m, mx);
            const float scale = __builtin_exp2f(m - mnew);
            m = mnew;
            l *= scale;
            #pragma unroll
            for (int reg = 0; reg < 4; ++reg) {
                const float sc_q = __shfl(scale, (lane & 48) | (hi * 4 + reg), 64);
                #pragma unroll
                for (int c2 = 0; c2 < 4; ++c2) o[c2][reg] *= sc_q;
            }
        }

        float lsum = 0.f;
        #pragma unroll
        for (int c = 0; c < 8; ++c)
            #pragma unroll
            for (int reg = 0; reg < 4; ++reg) {
                const float pv = __builtin_exp2f(p[c][reg] - m);
                p[c][reg] = pv;
                lsum += pv;
            }
        l += lsum;

        #pragma unroll
        for (int c = 0; c < 8; ++c) {
            const int el = ql * KVB + c * 16 + hi * 4;
            uint2 pk;
            pk.x = (unsigned)bfb(p[c][0]) | ((unsigned)bfb(p[c][1]) << 16);
            pk.y = (unsigned)bfb(p[c][2]) | ((unsigned)bfb(p[c][3]) << 16);
            *(uint2*)&Ps[wv][swz(el, ql)] = pk;
        }

        __builtin_amdgcn_s_setprio(1);
        #pragma unroll
        for (int kk = 0; kk < 4; ++kk) {
            const bf16x8 pf = *(const bf16x8*)&Ps[wv][swz(ql * KVB + kk * 32 + hi * 8, ql)];
            #pragma unroll
            for (int c2 = 0; c2 < 4; ++c2) {
                const int vrow = c2 * 16 + ql;
                const bf16x8 vf = *(const bf16x8*)&Vs[swz(vrow * KVB + kk * 32 + hi * 8, vrow)];
                o[c2] = __builtin_amdgcn_mfma_f32_16x16x32_bf16(pf, vf, o[c2], 0, 0, 0);
            }
        }
        __builtin_amdgcn_s_setprio(0);

        if (t < 7) {
            __syncthreads();
            stageKV((t + 1) * KVB);
            __syncthreads();
        }
    }

    l += __shfl_xor(l, 16, 64);
    l += __shfl_xor(l, 32, 64);
    const float invl = (l > 0.f) ? (1.0f / l) : 0.f;

    // O -> Ps[wv] ([16 rows][64 d] row-major) -> coalesced 128B-row stores
    #pragma unroll
    for (int reg = 0; reg < 4; ++reg) {
        const float inv_q = __shfl(invl, (lane & 48) | (hi * 4 + reg), 64);
        #pragma unroll
        for (int c2 = 0; c2 < 4; ++c2)
            Ps[wv][(hi * 4 + reg) * 64 + c2 * 16 + ql] = __float2bfloat16(o[c2][reg] * inv_q);
    }
    // wave-private LDS, in-order: no barrier needed
    #pragma unroll
    for (int p = 0; p < 2; ++p) {
        const int row = p * 8 + (lane >> 3);
        const int seg = (lane & 7) * 8;
        *(uint4*)&out[((size_t)(b * SEQ_L + q0 + wv * 16 + row)) * 512 + h * 64 + seg] =
            *(const uint4*)&Ps[wv][row * 64 + seg];
    }
}

// ------------------------------------------------------------------
// h1b = bf16(LayerNorm(h fp32 + projb bf16))
// ------------------------------------------------------------------
__global__ __launch_bounds__(256) void add_ln_to_bf16(
    const float* __restrict__ X, const bf16* __restrict__ Yb,
    const float* __restrict__ gamma, const float* __restrict__ beta,
    bf16* __restrict__ outb)
{
    const int wave = threadIdx.x >> 6;
    const int lane = threadIdx.x & 63;
    const int row = blockIdx.x * 4 + wave;
    const float* xp = X + (size_t)row * 512 + lane * 8;
    const bf16x8 yv = *(const bf16x8*)&Yb[(size_t)row * 512 + lane * 8];

    float v[8];
    const float4 a0 = *(const float4*)xp;
    const float4 a1 = *(const float4*)(xp + 4);
    v[0] = a0.x + (float)yv[0]; v[1] = a0.y + (float)yv[1];
    v[2] = a0.z + (float)yv[2]; v[3] = a0.w + (float)yv[3];
    v[4] = a1.x + (float)yv[4]; v[5] = a1.y + (float)yv[5];
    v[6] = a1.z + (float)yv[6]; v[7] = a1.w + (float)yv[7];

    float s = 0.f, sq = 0.f;
    #pragma unroll
    for (int i = 0; i < 8; ++i) { s += v[i]; sq += v[i] * v[i]; }
    #pragma unroll
    for (int off = 1; off < 64; off <<= 1) {
        s += __shfl_xor(s, off, 64);
        sq += __shfl_xor(sq, off, 64);
    }
    const float mu = s * (1.f / 512.f);
    const float var = sq * (1.f / 512.f) - mu * mu;
    const float rstd = rsqrtf(var + EPS);

    const int c = lane * 8;
    const float4 g0 = *(const float4*)&gamma[c];
    const float4 g1 = *(const float4*)&gamma[c + 4];
    const float4 e0 = *(const float4*)&beta[c];
    const float4 e1 = *(const float4*)&beta[c + 4];
    float r[8];
    r[0] = (v[0] - mu) * rstd * g0.x + e0.x;
    r[1] = (v[1] - mu) * rstd * g0.y + e0.y;
    r[2] = (v[2] - mu) * rstd * g0.z + e0.z;
    r[3] = (v[3] - mu) * rstd * g0.w + e0.w;
    r[4] = (v[4] - mu) * rstd * g1.x + e1.x;
    r[5] = (v[5] - mu) * rstd * g1.y + e1.y;
    r[6] = (v[6] - mu) * rstd * g1.z + e1.z;
    r[7] = (v[7] - mu) * rstd * g1.w + e1.w;

    uint4 w;
    w.x = (unsigned)bfb(r[0]) | ((unsigned)bfb(r[1]) << 16);
    w.y = (unsigned)bfb(r[2]) | ((unsigned)bfb(r[3]) << 16);
    w.z = (unsigned)bfb(r[4]) | ((unsigned)bfb(r[5]) << 16);
    w.w = (unsigned)bfb(r[6]) | ((unsigned)bfb(r[7]) << 16);
    *(uint4*)&outb[(size_t)row * 512 + c] = w;
}

// ------------------------------------------------------------------
// out fp32 = LayerNorm(h1b bf16 + f2b bf16)
// ------------------------------------------------------------------
__global__ __launch_bounds__(256) void add_ln_from_bf16(
    const bf16* __restrict__ Xb, const bf16* __restrict__ Yb,
    const float* __restrict__ gamma, const float* __restrict__ beta,
    float* __restrict__ out)
{
    const int wave = threadIdx.x >> 6;
    const int lane = threadIdx.x & 63;
    const int row = blockIdx.x * 4 + wave;
    const bf16x8 xv = *(const bf16x8*)&Xb[(size_t)row * 512 + lane * 8];
    const bf16x8 yv = *(const bf16x8*)&Yb[(size_t)row * 512 + lane * 8];

    float v[8];
    #pragma unroll
    for (int i = 0; i < 8; ++i) v[i] = (float)xv[i] + (float)yv[i];

    float s = 0.f, sq = 0.f;
    #pragma unroll
    for (int i = 0; i < 8; ++i) { s += v[i]; sq += v[i] * v[i]; }
    #pragma unroll
    for (int off = 1; off < 64; off <<= 1) {
        s += __shfl_xor(s, off, 64);
        sq += __shfl_xor(sq, off, 64);
    }
    const float mu = s * (1.f / 512.f);
    const float var = sq * (1.f / 512.f) - mu * mu;
    const float rstd = rsqrtf(var + EPS);

    const int c = lane * 8;
    const float4 g0 = *(const float4*)&gamma[c];
    const float4 g1 = *(const float4*)&gamma[c + 4];
    const float4 e0 = *(const float4*)&beta[c];
    const float4 e1 = *(const float4*)&beta[c + 4];
    float4 r0, r1;
    r0.x = (v[0] - mu) * rstd * g0.x + e0.x;
    r0.y = (v[1] - mu) * rstd * g0.y + e0.y;
    r0.z = (v[2] - mu) * rstd * g0.z + e0.z;
    r0.w = (v[3] - mu) * rstd * g0.w + e0.w;
    r1.x = (v[4] - mu) * rstd * g1.x + e1.x;
    r1.y = (v[5] - mu) * rstd * g1.y + e1.y;
    r1.z = (v[6] - mu) * rstd * g1.z + e1.z;
    r1.w = (v[7] - mu) * rstd * g1.w + e1.w;
    float* op = out + (size_t)row * 512 + c;
    *(float4*)op = r0;
    *(float4*)(op + 4) = r1;
}

// ------------------------------------------------------------------
extern "C" void kernel_launch(void* const* d_in, const int* in_sizes, int n_in,
                              void* d_out, int out_size, void* d_ws, size_t ws_size,
                              hipStream_t stream)
{
    const float* h    = (const float*)d_in[0];
    const float* ab   = (const float*)d_in[1];
    const int*   mask = (const int*)d_in[2];
    const float* Wqkv = (const float*)d_in[3];
    const float* bqkv = (const float*)d_in[4];
    const float* Wo   = (const float*)d_in[5];
    const float* bo   = (const float*)d_in[6];
    const float* W1   = (const float*)d_in[7];
    const float* b1   = (const float*)d_in[8];
    const float* W2   = (const float*)d_in[9];
    const float* b2   = (const float*)d_in[10];
    const float* g1   = (const float*)d_in[11];
    const float* be1  = (const float*)d_in[12];
    const float* g2   = (const float*)d_in[13];
    const float* be2  = (const float*)d_in[14];
    float* out = (float*)d_out;
    char* ws = (char*)d_ws;

    const int M = 8 * 1024;
    const size_t MB = 1024 * 1024;

    bf16*  hb    = (bf16*)(ws + 0 * MB);    // 8MB
    bf16*  Wtq   = (bf16*)(ws + 8 * MB);    // 1.5MB
    bf16*  Wto   = (bf16*)(ws + 10 * MB);   // 0.5MB
    bf16*  Wt1   = (bf16*)(ws + 11 * MB);   // 2MB
    bf16*  Wt2   = (bf16*)(ws + 13 * MB);   // 2MB
    bf16*  Qb    = (bf16*)(ws + 15 * MB);   // 8MB
    bf16*  Kb    = (bf16*)(ws + 23 * MB);   // 8MB
    bf16*  Vtb   = (bf16*)(ws + 31 * MB);   // 8MB
    bf16*  aob   = (bf16*)(ws + 39 * MB);   // 8MB
    bf16*  projb = (bf16*)(ws + 47 * MB);   // 8MB
    bf16*  h1b   = (bf16*)(ws + 55 * MB);   // 8MB
    bf16*  ffb   = (bf16*)(ws + 63 * MB);   // 32MB
    bf16*  f2b   = (bf16*)(ws + 95 * MB);   // 8MB

    prep_kernel<<<dim3(5120), 256, 0, stream>>>(h, Wqkv, Wo, W1, W2, hb, Wtq, Wto, Wt1, Wt2);
    gemm_qkv<<<dim3(M / 128, 1536 / 128), 256, 0, stream>>>(hb, Wtq, bqkv, Qb, Kb, Vtb, M, 1536, 512);
    attn_mfma<<<dim3(64, SEQ_L / 128), 512, 0, stream>>>(Qb, Kb, Vtb, ab, mask, aob);
    gemm_bf16<<<dim3(M / 128, 512 / 128), 256, 0, stream>>>(aob, Wto, bo, projb, M, 512, 512, 0);
    add_ln_to_bf16<<<dim3(M / 4), 256, 0, stream>>>(h, projb, g1, be1, h1b);
    gemm_bf16<<<dim3(M / 128, 2048 / 128), 256, 0, stream>>>(h1b, Wt1, b1, ffb, M, 2048, 512, 1);
    gemm_bf16<<<dim3(M / 128, 512 / 128), 256, 0, stream>>>(ffb, Wt2, b2, f2b, M, 512, 2048, 0);
    add_ln_from_bf16<<<dim3(M / 4), 256, 0, stream>>>(h1b, f2b, g2, be2, out);
}